// Round 2
// baseline (6834.520 us; speedup 1.0000x reference)
//
#include <hip/hip_runtime.h>

// ---------------------------------------------------------------------------
// TSP transformer stack: 6 layers of {selfattn -> LN, crossattn(tanh-clip,mask)
// -> LN, FFN -> LN}. bf16 MFMA compute, fp32 residual stream / accumulation.
// Workspace-adaptive: chunk rows (whole batches) so scratch fits ws_size.
// ---------------------------------------------------------------------------

typedef __bf16 bf16_t;
typedef __bf16 bf16x8 __attribute__((ext_vector_type(8)));
typedef __bf16 bf16x4 __attribute__((ext_vector_type(4)));
typedef float  f32x4  __attribute__((ext_vector_type(4)));

#define NB   64
#define NS   512
#define ND   512
#define NH   8
#define NHD  64
#define NL   6
#define NDFF 2048
#define NM   (NB * NS)   // 32768 rows

__device__ __forceinline__ void gld_lds16(const void* gsrc, void* lds) {
  // async global->LDS, 16B per lane; LDS dest is wave-uniform base + lane*16
  __builtin_amdgcn_global_load_lds((__attribute__((address_space(1))) void*)gsrc,
                                   (__attribute__((address_space(3))) void*)lds,
                                   16, 0, 0);
}

// ------------------------------ f32 -> bf16 --------------------------------
__global__ __launch_bounds__(256) void cvt_f32_bf16(const float* __restrict__ in,
                                                    bf16_t* __restrict__ out,
                                                    long n) {
  long i = ((long)blockIdx.x * 256 + threadIdx.x) * 8;
  const long stride = (long)gridDim.x * 256 * 8;
  for (; i < n; i += stride) {
    f32x4 a = *(const f32x4*)(in + i);
    f32x4 b = *(const f32x4*)(in + i + 4);
    bf16x8 o;
#pragma unroll
    for (int j = 0; j < 4; ++j) { o[j] = (bf16_t)a[j]; o[j + 4] = (bf16_t)b[j]; }
    *(bf16x8*)(out + i) = o;
  }
}

// --------------------- GEMM: C[M][N] = A[M][K] @ W[N][K]^T + bias ----------
// m97 structure: 128x128 tile, BK=64, 4 waves (2x2), 16x16x32 bf16 MFMA.
template<bool OUT_BF16, bool RELU>
__global__ __launch_bounds__(256) void gemm_bt(const bf16_t* __restrict__ A,
                                               const bf16_t* __restrict__ W,
                                               const float* __restrict__ bias,
                                               void* __restrict__ Cout,
                                               int Nn, int Kk) {
  __shared__ __attribute__((aligned(16))) bf16_t As[128 * 64];
  __shared__ __attribute__((aligned(16))) bf16_t Bs[128 * 64];
  const int tid = threadIdx.x;
  const int l   = tid & 63;
  const int w   = tid >> 6;
  const int wr  = (w >> 1) * 64;
  const int wc  = (w & 1) * 64;
  const int m0  = blockIdx.x * 128;
  const int n0  = blockIdx.y * 128;
  const int l15 = l & 15, lg = l >> 4;

  const f32x4 zero = {0.f, 0.f, 0.f, 0.f};
  f32x4 acc[4][4];
#pragma unroll
  for (int i = 0; i < 4; ++i)
#pragma unroll
    for (int j = 0; j < 4; ++j) acc[i][j] = zero;

  const int srow = w * 32 + (l >> 3);   // staging row within tile
  const int scol = (l & 7) * 8;         // staging col (8 bf16 = 16B)

  for (int k0 = 0; k0 < Kk; k0 += 64) {
#pragma unroll
    for (int i = 0; i < 4; ++i) {
      gld_lds16(A + (size_t)(m0 + srow + i * 8) * Kk + k0 + scol, &As[(w * 4 + i) * 512]);
      gld_lds16(W + (size_t)(n0 + srow + i * 8) * Kk + k0 + scol, &Bs[(w * 4 + i) * 512]);
    }
    __syncthreads();
#pragma unroll
    for (int kk = 0; kk < 2; ++kk) {
      bf16x8 af[4], bw[4];
#pragma unroll
      for (int i = 0; i < 4; ++i) {
        af[i] = *(const bf16x8*)&As[(wr + i * 16 + l15) * 64 + kk * 32 + lg * 8];
        bw[i] = *(const bf16x8*)&Bs[(wc + i * 16 + l15) * 64 + kk * 32 + lg * 8];
      }
#pragma unroll
      for (int mi = 0; mi < 4; ++mi)
#pragma unroll
        for (int ni = 0; ni < 4; ++ni)
          acc[mi][ni] = __builtin_amdgcn_mfma_f32_16x16x32_bf16(af[mi], bw[ni], acc[mi][ni], 0, 0, 0);
    }
    __syncthreads();
  }

#pragma unroll
  for (int mi = 0; mi < 4; ++mi)
#pragma unroll
    for (int ni = 0; ni < 4; ++ni) {
      const int col = n0 + wc + ni * 16 + l15;
      const float bv = bias[col];
#pragma unroll
      for (int r = 0; r < 4; ++r) {
        const size_t row = (size_t)(m0 + wr + mi * 16 + lg * 4 + r);
        float v = acc[mi][ni][r] + bv;
        if (RELU) v = fmaxf(v, 0.f);
        if (OUT_BF16) ((bf16_t*)Cout)[row * Nn + col] = (bf16_t)v;
        else          ((float*)Cout)[row * Nn + col]  = v;
      }
    }
}

// ------------------------------- attention ---------------------------------
// One WG = (local batch, head, 64-row Q tile), 4 waves x 16 q-rows. Full-row
// scores in registers, wave-parallel softmax, P in XOR-swizzled LDS, V
// transposed into XOR-swizzled LDS for contiguous b-frags.
template<int CROSS>
__global__ __launch_bounds__(256) void attn_kernel(const bf16_t* __restrict__ Qg,
                                                   const bf16_t* __restrict__ Kg,
                                                   const bf16_t* __restrict__ Vg,
                                                   const float* __restrict__ maskp,
                                                   float* __restrict__ O,
                                                   int qstride, int kstride) {
  __shared__ __attribute__((aligned(16))) bf16_t kv_s[128 * 64];  // K tile / V^T tile
  __shared__ __attribute__((aligned(16))) bf16_t p_s[64 * 512];   // P (bf16, swizzled)

  const int tid = threadIdx.x;
  const int l   = tid & 63;
  const int w   = tid >> 6;
  const int bid = blockIdx.x;
  const int qt  = bid & 7;
  const int h   = (bid >> 3) & 7;
  const int b   = bid >> 6;            // chunk-local batch
  const int h64 = h * NHD;
  const int l15 = l & 15, lg = l >> 4;

  const size_t qbase    = (size_t)(b * NS + qt * 64 + w * 16);
  const size_t krowbase = (size_t)b * NS;

  // Q fragments: A[m=l15][k = f*32 + lg*8 + j]
  bf16x8 qf[2];
#pragma unroll
  for (int f = 0; f < 2; ++f)
    qf[f] = *(const bf16x8*)(Qg + (qbase + l15) * qstride + h64 + f * 32 + lg * 8);

  f32x4 sc[4][8];   // [kt 128-chunk][nt 16-col tile]

  // ---- QK^T ----
#pragma unroll
  for (int kt = 0; kt < 4; ++kt) {
    // stage K tile [128][64] with XOR-swizzled SOURCE (rule 21)
#pragma unroll
    for (int i = 0; i < 4; ++i) {
      const int r  = (w * 4 + i) * 8 + (l >> 3);
      const int c8 = (l & 7) ^ (r & 7);
      gld_lds16(Kg + (krowbase + kt * 128 + r) * kstride + h64 + c8 * 8,
                &kv_s[(w * 4 + i) * 512]);
    }
    __syncthreads();
#pragma unroll
    for (int nt = 0; nt < 8; ++nt) {
      const int krow = nt * 16 + l15;
      bf16x8 kb0 = *(const bf16x8*)&kv_s[krow * 64 + ((lg ^ (krow & 7)) * 8)];
      bf16x8 kb1 = *(const bf16x8*)&kv_s[krow * 64 + ((((lg + 4)) ^ (krow & 7)) * 8)];
      f32x4 z = {0.f, 0.f, 0.f, 0.f};
      z = __builtin_amdgcn_mfma_f32_16x16x32_bf16(qf[0], kb0, z, 0, 0, 0);
      z = __builtin_amdgcn_mfma_f32_16x16x32_bf16(qf[1], kb1, z, 0, 0, 0);
      sc[kt][nt] = z;
    }
    __syncthreads();
  }

  // ---- scale (+ clip/mask for cross) ----
  const float scale = 0.125f;   // 1/sqrt(64)
#pragma unroll
  for (int kt = 0; kt < 4; ++kt)
#pragma unroll
    for (int nt = 0; nt < 8; ++nt) {
      f32x4 s = sc[kt][nt] * scale;
      if (CROSS) {
#pragma unroll
        for (int r = 0; r < 4; ++r) {
          const float e2 = __expf(2.f * s[r]);       // e^{2x}, x = s
          float t = 10.f - 20.f / (e2 + 1.f);        // 10*tanh(x)
          const int sq = qt * 64 + w * 16 + lg * 4 + r;
          const int sk = kt * 128 + nt * 16 + l15;
          t += maskp[((size_t)b * NS + sq) * NS + sk];
          s[r] = t;
        }
      }
      sc[kt][nt] = s;
    }

  // ---- softmax (rows spread over the 16 lanes sharing lg) ----
  float mx[4] = {-1e30f, -1e30f, -1e30f, -1e30f};
#pragma unroll
  for (int kt = 0; kt < 4; ++kt)
#pragma unroll
    for (int nt = 0; nt < 8; ++nt)
#pragma unroll
      for (int r = 0; r < 4; ++r) mx[r] = fmaxf(mx[r], sc[kt][nt][r]);
#pragma unroll
  for (int r = 0; r < 4; ++r)
#pragma unroll
    for (int off = 1; off < 16; off <<= 1)
      mx[r] = fmaxf(mx[r], __shfl_xor(mx[r], off, 64));

  float sm[4] = {0.f, 0.f, 0.f, 0.f};
#pragma unroll
  for (int kt = 0; kt < 4; ++kt)
#pragma unroll
    for (int nt = 0; nt < 8; ++nt) {
      f32x4 s = sc[kt][nt];
#pragma unroll
      for (int r = 0; r < 4; ++r) { const float e = __expf(s[r] - mx[r]); sm[r] += e; s[r] = e; }
      sc[kt][nt] = s;
    }
#pragma unroll
  for (int r = 0; r < 4; ++r)
#pragma unroll
    for (int off = 1; off < 16; off <<= 1)
      sm[r] += __shfl_xor(sm[r], off, 64);
  float inv[4];
#pragma unroll
  for (int r = 0; r < 4; ++r) inv[r] = 1.f / sm[r];

  // ---- write P (normalized, bf16) to swizzled LDS ----
#pragma unroll
  for (int kt = 0; kt < 4; ++kt)
#pragma unroll
    for (int nt = 0; nt < 8; ++nt)
#pragma unroll
      for (int r = 0; r < 4; ++r) {
        const int prow = w * 16 + lg * 4 + r;
        const int pcol = kt * 128 + nt * 16 + l15;
        const int off  = (prow * 1024 + pcol * 2) ^ ((prow & 7) << 4);
        *(bf16_t*)((char*)p_s + off) = (bf16_t)(sc[kt][nt][r] * inv[r]);
      }

  // ---- PV ----
  const f32x4 zz = {0.f, 0.f, 0.f, 0.f};
  f32x4 oacc[4] = {zz, zz, zz, zz};
  const int vk  = tid & 127;            // k-row within 128 tile
  const int vdh = (tid >> 7) * 32;      // d half

  for (int vt = 0; vt < 4; ++vt) {
    const bf16_t* vrow = Vg + (krowbase + vt * 128 + vk) * kstride + h64 + vdh;
    bf16x8 vv0 = *(const bf16x8*)(vrow);
    bf16x8 vv1 = *(const bf16x8*)(vrow + 8);
    bf16x8 vv2 = *(const bf16x8*)(vrow + 16);
    bf16x8 vv3 = *(const bf16x8*)(vrow + 24);
    __syncthreads();   // prior phase's reads of kv_s / p_s writes visible
#pragma unroll
    for (int jj = 0; jj < 4; ++jj) {
      bf16x8 bb = (jj == 0) ? vv0 : (jj == 1) ? vv1 : (jj == 2) ? vv2 : vv3;
#pragma unroll
      for (int e = 0; e < 8; ++e) {
        const int d   = vdh + jj * 8 + e;
        const int off = (d * 256 + vk * 2) ^ ((d & 7) << 4);
        *(bf16_t*)((char*)kv_s + off) = bb[e];
      }
    }
    __syncthreads();
#pragma unroll
    for (int ks = 0; ks < 4; ++ks) {
      const int prow = w * 16 + l15;
      const int aoff = (prow * 1024 + (vt * 128 + ks * 32 + lg * 8) * 2) ^ ((prow & 7) << 4);
      bf16x8 pa = *(const bf16x8*)((char*)p_s + aoff);
#pragma unroll
      for (int nt = 0; nt < 4; ++nt) {
        const int n    = nt * 16 + l15;
        const int boff = (n * 256 + (ks * 32 + lg * 8) * 2) ^ ((n & 7) << 4);
        bf16x8 vb = *(const bf16x8*)((char*)kv_s + boff);
        oacc[nt] = __builtin_amdgcn_mfma_f32_16x16x32_bf16(pa, vb, oacc[nt], 0, 0, 0);
      }
    }
  }

  // ---- write O (f32) ----
#pragma unroll
  for (int nt = 0; nt < 4; ++nt)
#pragma unroll
    for (int r = 0; r < 4; ++r) {
      const size_t row = (size_t)(b * NS + qt * 64 + w * 16 + lg * 4 + r);
      O[row * ND + h64 + nt * 16 + l15] = oacc[nt][r];
    }
}

// --------------------------- fused add + LayerNorm -------------------------
__global__ __launch_bounds__(256) void add_ln_kernel(const float* __restrict__ Xa,
                                                     const float* __restrict__ Xb,
                                                     const float* __restrict__ gw,
                                                     const float* __restrict__ bw,
                                                     float* __restrict__ o32,
                                                     bf16_t* __restrict__ o16) {
  const int l = threadIdx.x & 63;
  const size_t row = (size_t)blockIdx.x * 4 + (threadIdx.x >> 6);
  const f32x4* pa = (const f32x4*)(Xa + row * ND);
  const f32x4* pb = (const f32x4*)(Xb + row * ND);
  f32x4 v0 = pa[l] + pb[l];
  f32x4 v1 = pa[l + 64] + pb[l + 64];
  float s = v0[0] + v0[1] + v0[2] + v0[3] + v1[0] + v1[1] + v1[2] + v1[3];
#pragma unroll
  for (int off = 1; off < 64; off <<= 1) s += __shfl_xor(s, off, 64);
  const float mean = s * (1.f / ND);
  f32x4 d0 = v0 - mean, d1 = v1 - mean;
  float q = d0[0]*d0[0] + d0[1]*d0[1] + d0[2]*d0[2] + d0[3]*d0[3]
          + d1[0]*d1[0] + d1[1]*d1[1] + d1[2]*d1[2] + d1[3]*d1[3];
#pragma unroll
  for (int off = 1; off < 64; off <<= 1) q += __shfl_xor(q, off, 64);
  const float rstd = rsqrtf(q * (1.f / ND) + 1e-5f);
  const f32x4 g0 = ((const f32x4*)gw)[l], g1 = ((const f32x4*)gw)[l + 64];
  const f32x4 b0 = ((const f32x4*)bw)[l], b1 = ((const f32x4*)bw)[l + 64];
  f32x4 r0 = d0 * rstd * g0 + b0;
  f32x4 r1 = d1 * rstd * g1 + b1;
  ((f32x4*)(o32 + row * ND))[l]      = r0;
  ((f32x4*)(o32 + row * ND))[l + 64] = r1;
  bf16x4 c0, c1;
#pragma unroll
  for (int i = 0; i < 4; ++i) { c0[i] = (bf16_t)r0[i]; c1[i] = (bf16_t)r1[i]; }
  *(bf16x4*)(o16 + row * ND + l * 4)       = c0;
  *(bf16x4*)(o16 + row * ND + 256 + l * 4) = c1;
}

// ---------------------------------------------------------------------------
extern "C" void kernel_launch(void* const* d_in, const int* in_sizes, int n_in,
                              void* d_out, int out_size, void* d_ws, size_t ws_size,
                              hipStream_t stream) {
  (void)in_sizes; (void)n_in; (void)out_size;
  const float* x     = (const float*)d_in[0];
  const float* maskp = (const float*)d_in[1];
  const float* qkvw  = (const float*)d_in[2];
  const float* qkvb  = (const float*)d_in[3];
  const float* ln1g  = (const float*)d_in[4];
  const float* ln1b  = (const float*)d_in[5];
  const float* kvw   = (const float*)d_in[6];
  const float* kvb   = (const float*)d_in[7];
  const float* ln2g  = (const float*)d_in[8];
  const float* ln2b  = (const float*)d_in[9];
  const float* w1p   = (const float*)d_in[10];
  const float* b1p   = (const float*)d_in[11];
  const float* w2p   = (const float*)d_in[12];
  const float* b2p   = (const float*)d_in[13];
  const float* ln3g  = (const float*)d_in[14];
  const float* ln3b  = (const float*)d_in[15];
  float* out = (float*)d_out;

  // ---- workspace tier selection (deterministic: depends on ws_size only) ----
  // need = weights + h16(full M) + R*11264 (chunk scratch) + slack
  const size_t WALL = 40894464, WLYR = 6815744, H16B = 33554432;
  struct Tier { int R; bool allw; };
  const Tier tiers[5] = {{32768, true}, {8192, true}, {4096, true},
                         {2048, false}, {1024, false}};
  int R = 0; bool allw = false;
  for (int t = 0; t < 5; ++t) {
    size_t need = (tiers[t].allw ? WALL : WLYR) + H16B +
                  (size_t)tiers[t].R * 11264 + 8192;
    if (ws_size >= need) { R = tiers[t].R; allw = tiers[t].allw; break; }
  }
  if (R == 0) return;  // cannot run in this workspace
  const int nchunks = NM / R;
  const int CB = R / NS;               // batches per chunk

  char* p = (char*)d_ws;
  auto alloc = [&](size_t bytes) { char* r = p; p += (bytes + 255) & ~(size_t)255; return r; };
  bf16_t* WQ = (bf16_t*)alloc(allw ? (size_t)NL * 1536 * ND * 2 : (size_t)1536 * ND * 2);
  bf16_t* WK = (bf16_t*)alloc(allw ? (size_t)NL * 1024 * ND * 2 : (size_t)1024 * ND * 2);
  bf16_t* W1 = (bf16_t*)alloc(allw ? (size_t)NL * NDFF * ND * 2 : (size_t)NDFF * ND * 2);
  bf16_t* W2 = (bf16_t*)alloc(allw ? (size_t)NL * ND * NDFF * 2 : (size_t)ND * NDFF * 2);
  bf16_t* h16  = (bf16_t*)alloc((size_t)NM * ND * 2);
  bf16_t* big  = (bf16_t*)alloc((size_t)R * NDFF * 2);   // qkv / kv / ff1
  float*  t32  = (float*)alloc((size_t)R * ND * 4);      // attn out / ff2 out
  float*  x132 = (float*)alloc((size_t)R * ND * 4);
  bf16_t* x116 = (bf16_t*)alloc((size_t)R * ND * 2);
  float*  y32  = (float*)alloc((size_t)R * ND * 4);
  bf16_t* y16  = (bf16_t*)alloc((size_t)R * ND * 2);

  auto cvt = [&](const float* src, bf16_t* dst, long n) {
    int blocks = (int)((n / 8 + 255) / 256); if (blocks > 8192) blocks = 8192;
    hipLaunchKernelGGL(cvt_f32_bf16, dim3(blocks), dim3(256), 0, stream, src, dst, n);
  };

  cvt(x, h16, (long)NM * ND);
  if (allw) {
    cvt(qkvw, WQ, (long)NL * 1536 * ND);
    cvt(kvw,  WK, (long)NL * 1024 * ND);
    cvt(w1p,  W1, (long)NL * NDFF * ND);
    cvt(w2p,  W2, (long)NL * ND * NDFF);
  }

  for (int l = 0; l < NL; ++l) {
    const bf16_t *wq_l, *wk_l, *w1_l, *w2_l;
    if (allw) {
      wq_l = WQ + (size_t)l * 1536 * ND;
      wk_l = WK + (size_t)l * 1024 * ND;
      w1_l = W1 + (size_t)l * NDFF * ND;
      w2_l = W2 + (size_t)l * ND * NDFF;
    } else {
      cvt(qkvw + (size_t)l * 1536 * ND, WQ, (long)1536 * ND);
      cvt(kvw  + (size_t)l * 1024 * ND, WK, (long)1024 * ND);
      cvt(w1p  + (size_t)l * NDFF * ND, W1, (long)NDFF * ND);
      cvt(w2p  + (size_t)l * ND * NDFF, W2, (long)ND * NDFF);
      wq_l = WQ; wk_l = WK; w1_l = W1; w2_l = W2;
    }

    for (int c = 0; c < nchunks; ++c) {
      const size_t r0 = (size_t)c * R;
      const bf16_t* h16c = h16 + r0 * ND;
      const float*  resc = (l == 0 ? x : (const float*)out) + r0 * ND;
      float*        outc = out + r0 * ND;
      const float*  maskc = maskp + r0 * NS;   // (r0/512) batches * 512*512

      // 1) qkv = h @ qkv_w^T + b      (R x 1536, bf16)
      hipLaunchKernelGGL(HIP_KERNEL_NAME(gemm_bt<true, false>), dim3(R / 128, 12), dim3(256), 0, stream,
                         h16c, wq_l, qkvb + l * 1536, (void*)big, 1536, 512);
      // 2) self-attention -> t32
      hipLaunchKernelGGL(HIP_KERNEL_NAME(attn_kernel<0>), dim3(CB * 64), dim3(256), 0, stream,
                         big, big + 512, big + 1024, (const float*)nullptr, t32, 1536, 1536);
      // 3) x1 = LN1(h + attn)
      hipLaunchKernelGGL(add_ln_kernel, dim3(R / 4), dim3(256), 0, stream,
                         resc, t32, ln1g + l * ND, ln1b + l * ND, x132, x116);
      // 4) kv = h @ kv_w^T + b        (R x 1024, bf16)
      hipLaunchKernelGGL(HIP_KERNEL_NAME(gemm_bt<true, false>), dim3(R / 128, 8), dim3(256), 0, stream,
                         h16c, wk_l, kvb + l * 1024, (void*)big, 1024, 512);
      // 5) cross-attention (10*tanh + mask) -> t32
      hipLaunchKernelGGL(HIP_KERNEL_NAME(attn_kernel<1>), dim3(CB * 64), dim3(256), 0, stream,
                         x116, big, big + 512, maskc, t32, 512, 1024);
      // 6) y = LN2(x1 + attn)
      hipLaunchKernelGGL(add_ln_kernel, dim3(R / 4), dim3(256), 0, stream,
                         x132, t32, ln2g + l * ND, ln2b + l * ND, y32, y16);
      // 7) ff1 = relu(y @ w1^T + b1)  (R x 2048, bf16)
      hipLaunchKernelGGL(HIP_KERNEL_NAME(gemm_bt<true, true>), dim3(R / 128, 16), dim3(256), 0, stream,
                         y16, w1_l, b1p + l * NDFF, (void*)big, 2048, 512);
      // 8) ff2 = ff1 @ w2^T + b2      (R x 512, f32)
      hipLaunchKernelGGL(HIP_KERNEL_NAME(gemm_bt<false, false>), dim3(R / 128, 4), dim3(256), 0, stream,
                         big, w2_l, b2p + l * ND, (void*)t32, 512, 2048);
      // 9) h' = LN3(y + ff2) -> residual (d_out) + h16
      hipLaunchKernelGGL(add_ln_kernel, dim3(R / 4), dim3(256), 0, stream,
                         y32, t32, ln3g + l * ND, ln3b + l * ND, outc, h16 + r0 * ND);
    }
  }
}

// Round 3
// 4977.274 us; speedup vs baseline: 1.3731x; 1.3731x over previous
//
#include <hip/hip_runtime.h>

// ---------------------------------------------------------------------------
// TSP transformer stack: 6 layers of {selfattn -> LN, crossattn(tanh-clip,mask)
// -> LN, FFN -> LN}. bf16 MFMA compute, fp32 residual stream / accumulation.
// R2: swapped-QK attention (P-row lane-local), V^T produced by GEMM, online
// softmax, 48KB LDS attn; slimmer workspace tiers.
// ---------------------------------------------------------------------------

typedef __bf16 bf16_t;
typedef __bf16 bf16x8 __attribute__((ext_vector_type(8)));
typedef __bf16 bf16x4 __attribute__((ext_vector_type(4)));
typedef float  f32x4  __attribute__((ext_vector_type(4)));

#define NB   64
#define NS   512
#define ND   512
#define NH   8
#define NHD  64
#define NL   6
#define NDFF 2048
#define NM   (NB * NS)   // 32768 rows

__device__ __forceinline__ void gld_lds16(const void* gsrc, void* lds) {
  __builtin_amdgcn_global_load_lds((__attribute__((address_space(1))) void*)gsrc,
                                   (__attribute__((address_space(3))) void*)lds,
                                   16, 0, 0);
}

// ------------------------------ f32 -> bf16 --------------------------------
__global__ __launch_bounds__(256) void cvt_f32_bf16(const float* __restrict__ in,
                                                    bf16_t* __restrict__ out,
                                                    long n) {
  long i = ((long)blockIdx.x * 256 + threadIdx.x) * 8;
  const long stride = (long)gridDim.x * 256 * 8;
  for (; i < n; i += stride) {
    f32x4 a = *(const f32x4*)(in + i);
    f32x4 b = *(const f32x4*)(in + i + 4);
    bf16x8 o;
#pragma unroll
    for (int j = 0; j < 4; ++j) { o[j] = (bf16_t)a[j]; o[j + 4] = (bf16_t)b[j]; }
    *(bf16x8*)(out + i) = o;
  }
}

// --------------------- GEMM: C[M][N] = A[M][K] @ W[N][K]^T + bias ----------
// m97 structure: 128x128 tile, BK=64, 4 waves (2x2), 16x16x32 bf16 MFMA.
// BIAS_ROW: bias indexed by output ROW (used for the V^T = Wv @ h^T GEMM).
template<bool OUT_BF16, bool RELU, bool BIAS_ROW>
__global__ __launch_bounds__(256) void gemm_bt(const bf16_t* __restrict__ A,
                                               const bf16_t* __restrict__ W,
                                               const float* __restrict__ bias,
                                               void* __restrict__ Cout,
                                               int Nn, int Kk) {
  __shared__ __attribute__((aligned(16))) bf16_t As[128 * 64];
  __shared__ __attribute__((aligned(16))) bf16_t Bs[128 * 64];
  const int tid = threadIdx.x;
  const int l   = tid & 63;
  const int w   = tid >> 6;
  const int wr  = (w >> 1) * 64;
  const int wc  = (w & 1) * 64;
  const int m0  = blockIdx.x * 128;
  const int n0  = blockIdx.y * 128;
  const int l15 = l & 15, lg = l >> 4;

  const f32x4 zero = {0.f, 0.f, 0.f, 0.f};
  f32x4 acc[4][4];
#pragma unroll
  for (int i = 0; i < 4; ++i)
#pragma unroll
    for (int j = 0; j < 4; ++j) acc[i][j] = zero;

  const int srow = w * 32 + (l >> 3);   // staging row within tile
  const int scol = (l & 7) * 8;         // staging col (8 bf16 = 16B)

  for (int k0 = 0; k0 < Kk; k0 += 64) {
#pragma unroll
    for (int i = 0; i < 4; ++i) {
      gld_lds16(A + (size_t)(m0 + srow + i * 8) * Kk + k0 + scol, &As[(w * 4 + i) * 512]);
      gld_lds16(W + (size_t)(n0 + srow + i * 8) * Kk + k0 + scol, &Bs[(w * 4 + i) * 512]);
    }
    __syncthreads();
#pragma unroll
    for (int kk = 0; kk < 2; ++kk) {
      bf16x8 af[4], bw[4];
#pragma unroll
      for (int i = 0; i < 4; ++i) {
        af[i] = *(const bf16x8*)&As[(wr + i * 16 + l15) * 64 + kk * 32 + lg * 8];
        bw[i] = *(const bf16x8*)&Bs[(wc + i * 16 + l15) * 64 + kk * 32 + lg * 8];
      }
#pragma unroll
      for (int mi = 0; mi < 4; ++mi)
#pragma unroll
        for (int ni = 0; ni < 4; ++ni)
          acc[mi][ni] = __builtin_amdgcn_mfma_f32_16x16x32_bf16(af[mi], bw[ni], acc[mi][ni], 0, 0, 0);
    }
    __syncthreads();
  }

#pragma unroll
  for (int mi = 0; mi < 4; ++mi)
#pragma unroll
    for (int ni = 0; ni < 4; ++ni) {
      const int col = n0 + wc + ni * 16 + l15;
      const float bcol = BIAS_ROW ? 0.f : bias[col];
#pragma unroll
      for (int r = 0; r < 4; ++r) {
        const int rowi = m0 + wr + mi * 16 + lg * 4 + r;
        float v = acc[mi][ni][r] + (BIAS_ROW ? bias[rowi] : bcol);
        if (RELU) v = fmaxf(v, 0.f);
        if (OUT_BF16) ((bf16_t*)Cout)[(size_t)rowi * Nn + col] = (bf16_t)v;
        else          ((float*)Cout)[(size_t)rowi * Nn + col]  = v;
      }
    }
}

// ------------------------------- attention ---------------------------------
// One WG = (local batch, head, 64-row Q tile), 4 waves x 16 q-rows.
// Swapped QK^T (mfma(K,Q)) -> lane holds 4 consecutive k per q -> b64 P-writes.
// V consumed pre-transposed (Vt[d][s]) and staged linearly via gld_lds.
// Online softmax over 4 k-tiles of 128.  LDS = 48KB -> 3 WG/CU.
template<int CROSS>
__global__ __launch_bounds__(256, 3) void attn2(const bf16_t* __restrict__ Q,
                                                const bf16_t* __restrict__ K,
                                                const bf16_t* __restrict__ Vt,
                                                const float* __restrict__ maskp,
                                                float* __restrict__ O,
                                                int qstride, int kstride, int vstride) {
  __shared__ __attribute__((aligned(16))) bf16_t k_s[128 * 64];  // [k][d]
  __shared__ __attribute__((aligned(16))) bf16_t v_s[64 * 128];  // [d][k]
  __shared__ __attribute__((aligned(16))) bf16_t p_s[64 * 128];  // [q][k]

  const int tid = threadIdx.x;
  const int l   = tid & 63;
  const int w   = tid >> 6;
  const int bid = blockIdx.x;
  const int qt  = bid & 7;
  const int h   = (bid >> 3) & 7;
  const int b   = bid >> 6;            // chunk-local batch
  const int h64 = h * NHD;
  const int l15 = l & 15, lg = l >> 4;

  const int qglob = qt * 64 + w * 16 + l15;          // this lane's softmax q-row

  // Q fragments (B-operand): B[n=q(l15)][kd = c*32 + lg*8 + j]
  bf16x8 qf[2];
#pragma unroll
  for (int c = 0; c < 2; ++c)
    qf[c] = *(const bf16x8*)(Q + (size_t)(b * NS + qglob) * qstride + h64 + c * 32 + lg * 8);

  float m_run = -3e38f, l_run = 0.f;
  const f32x4 zz = {0.f, 0.f, 0.f, 0.f};
  f32x4 oacc[4] = {zz, zz, zz, zz};

  for (int kt = 0; kt < 4; ++kt) {
    // ---- stage K tile [128 k][64 d], source-swizzled (8 granules, ^row&7) ----
#pragma unroll
    for (int i = 0; i < 4; ++i) {
      const int r  = (w * 4 + i) * 8 + (l >> 3);
      const int c8 = (l & 7) ^ (r & 7);
      gld_lds16(K + (size_t)(b * NS + kt * 128 + r) * kstride + h64 + c8 * 8,
                &k_s[(w * 4 + i) * 512]);
    }
    // ---- stage V tile v_s[64 d][128 k] from Vt[d][s], src-swz (16 gran, ^d&15) ----
#pragma unroll
    for (int i = 0; i < 4; ++i) {
      const int d = w * 16 + i * 4 + (l >> 4);
      const int g = (l & 15) ^ (d & 15);
      gld_lds16(Vt + (size_t)(h64 + d) * vstride + b * NS + kt * 128 + g * 8,
                &v_s[(w * 16 + i * 4) * 128]);
    }
    __syncthreads();

    // ---- QK^T (swapped): s[nt] holds S[k = nt*16+lg*4+r][q = l15-local] ----
    f32x4 s[8];
#pragma unroll
    for (int nt = 0; nt < 8; ++nt) {
      const int row = nt * 16 + l15;   // k-row
      bf16x8 ka0 = *(const bf16x8*)((const char*)k_s + row * 128 + ((lg ^ (row & 7)) * 16));
      bf16x8 ka1 = *(const bf16x8*)((const char*)k_s + row * 128 + (((4 + lg) ^ (row & 7)) * 16));
      f32x4 z = zz;
      z = __builtin_amdgcn_mfma_f32_16x16x32_bf16(ka0, qf[0], z, 0, 0, 0);
      z = __builtin_amdgcn_mfma_f32_16x16x32_bf16(ka1, qf[1], z, 0, 0, 0);
      s[nt] = z;
    }

    // ---- scale (+clip/mask), online softmax update ----
    float tmax = -3e38f;
#pragma unroll
    for (int nt = 0; nt < 8; ++nt) {
      f32x4 v = s[nt] * 0.125f;        // 1/sqrt(64)
      if (CROSS) {
        const f32x4 mk = *(const f32x4*)(maskp + (size_t)(b * NS + qglob) * NS
                                         + kt * 128 + nt * 16 + lg * 4);
#pragma unroll
        for (int r = 0; r < 4; ++r) {
          const float e2 = __expf(2.f * v[r]);
          v[r] = 10.f - 20.f * __builtin_amdgcn_rcpf(e2 + 1.f) + mk[r];
        }
      }
      s[nt] = v;
#pragma unroll
      for (int r = 0; r < 4; ++r) tmax = fmaxf(tmax, v[r]);
    }
    tmax = fmaxf(tmax, __shfl_xor(tmax, 16, 64));
    tmax = fmaxf(tmax, __shfl_xor(tmax, 32, 64));
    const float m_new = fmaxf(m_run, tmax);
    const float f = __expf(m_run - m_new);
    float fq[4];
#pragma unroll
    for (int r = 0; r < 4; ++r) fq[r] = __shfl(f, lg * 4 + r, 64);
#pragma unroll
    for (int dt = 0; dt < 4; ++dt)
#pragma unroll
      for (int r = 0; r < 4; ++r) oacc[dt][r] *= fq[r];

    float ts = 0.f;
#pragma unroll
    for (int nt = 0; nt < 8; ++nt) {
      f32x4 v = s[nt];
#pragma unroll
      for (int r = 0; r < 4; ++r) { const float e = __expf(v[r] - m_new); ts += e; v[r] = e; }
      s[nt] = v;
    }
    l_run = l_run * f + ts;
    m_run = m_new;

    // ---- pack P (bf16) -> p_s rows w*16+l15, b64 writes, swz granule ^row&15 ----
    const int prow = w * 16 + l15;
#pragma unroll
    for (int nt = 0; nt < 8; ++nt) {
      bf16x4 pk;
#pragma unroll
      for (int r = 0; r < 4; ++r) pk[r] = (bf16_t)s[nt][r];
      const int gran = (nt * 2 + (lg >> 1)) ^ (prow & 15);
      *(bf16x4*)((char*)p_s + prow * 256 + gran * 16 + (lg & 1) * 8) = pk;
    }

    // ---- PV: oacc[dt] += P[q][k] * Vt[d][k] ----
#pragma unroll
    for (int ks = 0; ks < 4; ++ks) {
      const int ag = (ks * 4 + lg) ^ (prow & 15);
      bf16x8 pa = *(const bf16x8*)((const char*)p_s + prow * 256 + ag * 16);
#pragma unroll
      for (int dt = 0; dt < 4; ++dt) {
        const int vrow = dt * 16 + l15;
        const int vg   = (ks * 4 + lg) ^ (vrow & 15);
        bf16x8 vb = *(const bf16x8*)((const char*)v_s + vrow * 256 + vg * 16);
        oacc[dt] = __builtin_amdgcn_mfma_f32_16x16x32_bf16(pa, vb, oacc[dt], 0, 0, 0);
      }
    }
    __syncthreads();   // all LDS reads done before next kt staging
  }

  // ---- finalize: 1/rowsum, redistribute to O-layout rows, store f32 ----
  l_run += __shfl_xor(l_run, 16, 64);
  l_run += __shfl_xor(l_run, 32, 64);
  const float inv = 1.f / l_run;
  float invq[4];
#pragma unroll
  for (int r = 0; r < 4; ++r) invq[r] = __shfl(inv, lg * 4 + r, 64);
#pragma unroll
  for (int dt = 0; dt < 4; ++dt)
#pragma unroll
    for (int r = 0; r < 4; ++r) {
      const size_t row = (size_t)(b * NS + qt * 64 + w * 16 + lg * 4 + r);
      O[row * ND + h64 + dt * 16 + l15] = oacc[dt][r] * invq[r];
    }
}

// --------------------------- fused add + LayerNorm -------------------------
// NOTE: Xa and o32 may alias (in-place) -> no __restrict__ on them.
__global__ __launch_bounds__(256) void add_ln_kernel(const float* Xa,
                                                     const float* __restrict__ Xb,
                                                     const float* __restrict__ gw,
                                                     const float* __restrict__ bw,
                                                     float* o32,
                                                     bf16_t* __restrict__ o16) {
  const int l = threadIdx.x & 63;
  const size_t row = (size_t)blockIdx.x * 4 + (threadIdx.x >> 6);
  const f32x4* pa = (const f32x4*)(Xa + row * ND);
  const f32x4* pb = (const f32x4*)(Xb + row * ND);
  f32x4 v0 = pa[l] + pb[l];
  f32x4 v1 = pa[l + 64] + pb[l + 64];
  float s = v0[0] + v0[1] + v0[2] + v0[3] + v1[0] + v1[1] + v1[2] + v1[3];
#pragma unroll
  for (int off = 1; off < 64; off <<= 1) s += __shfl_xor(s, off, 64);
  const float mean = s * (1.f / ND);
  f32x4 d0 = v0 - mean, d1 = v1 - mean;
  float q = d0[0]*d0[0] + d0[1]*d0[1] + d0[2]*d0[2] + d0[3]*d0[3]
          + d1[0]*d1[0] + d1[1]*d1[1] + d1[2]*d1[2] + d1[3]*d1[3];
#pragma unroll
  for (int off = 1; off < 64; off <<= 1) q += __shfl_xor(q, off, 64);
  const float rstd = rsqrtf(q * (1.f / ND) + 1e-5f);
  const f32x4 g0 = ((const f32x4*)gw)[l], g1 = ((const f32x4*)gw)[l + 64];
  const f32x4 b0 = ((const f32x4*)bw)[l], b1 = ((const f32x4*)bw)[l + 64];
  f32x4 r0 = d0 * rstd * g0 + b0;
  f32x4 r1 = d1 * rstd * g1 + b1;
  ((f32x4*)(o32 + row * ND))[l]      = r0;
  ((f32x4*)(o32 + row * ND))[l + 64] = r1;
  bf16x4 c0, c1;
#pragma unroll
  for (int i = 0; i < 4; ++i) { c0[i] = (bf16_t)r0[i]; c1[i] = (bf16_t)r1[i]; }
  *(bf16x4*)(o16 + row * ND + l * 4)       = c0;
  *(bf16x4*)(o16 + row * ND + 256 + l * 4) = c1;
}

// ---------------------------------------------------------------------------
extern "C" void kernel_launch(void* const* d_in, const int* in_sizes, int n_in,
                              void* d_out, int out_size, void* d_ws, size_t ws_size,
                              hipStream_t stream) {
  (void)in_sizes; (void)n_in; (void)out_size;
  const float* x     = (const float*)d_in[0];
  const float* maskp = (const float*)d_in[1];
  const float* qkvw  = (const float*)d_in[2];
  const float* qkvb  = (const float*)d_in[3];
  const float* ln1g  = (const float*)d_in[4];
  const float* ln1b  = (const float*)d_in[5];
  const float* kvw   = (const float*)d_in[6];
  const float* kvb   = (const float*)d_in[7];
  const float* ln2g  = (const float*)d_in[8];
  const float* ln2b  = (const float*)d_in[9];
  const float* w1p   = (const float*)d_in[10];
  const float* b1p   = (const float*)d_in[11];
  const float* w2p   = (const float*)d_in[12];
  const float* b2p   = (const float*)d_in[13];
  const float* ln3g  = (const float*)d_in[14];
  const float* ln3b  = (const float*)d_in[15];
  float* out = (float*)d_out;

  // ---- workspace tiers: per-row = big 4096B + t32 2048 + x132 2048 + xy16 1024
  const size_t WALL = 40894464, WLYR = 6815744, H16B = 33554432;
  struct Tier { int R; bool allw; };
  const Tier tiers[6] = {{32768, true}, {16384, true}, {8192, true},
                         {4096, true}, {2048, false}, {1024, false}};
  int R = 0; bool allw = false;
  for (int t = 0; t < 6; ++t) {
    size_t need = (tiers[t].allw ? WALL : WLYR) + H16B +
                  (size_t)tiers[t].R * 9216 + 16384;
    if (ws_size >= need) { R = tiers[t].R; allw = tiers[t].allw; break; }
  }
  if (R == 0) return;
  const int nchunks = NM / R;
  const int CB = R / NS;               // batches per chunk

  char* p = (char*)d_ws;
  auto alloc = [&](size_t bytes) { char* r = p; p += (bytes + 255) & ~(size_t)255; return r; };
  bf16_t* WQ = (bf16_t*)alloc((allw ? NL : 1) * (size_t)1536 * ND * 2);
  bf16_t* WK = (bf16_t*)alloc((allw ? NL : 1) * (size_t)1024 * ND * 2);
  bf16_t* W1 = (bf16_t*)alloc((allw ? NL : 1) * (size_t)NDFF * ND * 2);
  bf16_t* W2 = (bf16_t*)alloc((allw ? NL : 1) * (size_t)ND * NDFF * 2);
  bf16_t* h16  = (bf16_t*)alloc((size_t)NM * ND * 2);
  bf16_t* big  = (bf16_t*)alloc((size_t)R * NDFF * 2);   // qk/kv + vt overlay + ff1
  float*  t32  = (float*)alloc((size_t)R * ND * 4);      // attn out / ff2 out
  float*  x132 = (float*)alloc((size_t)R * ND * 4);      // x1 f32, then y f32 in-place
  bf16_t* xy16 = (bf16_t*)alloc((size_t)R * ND * 2);     // x1 bf16, then y bf16

  auto cvt = [&](const float* src, bf16_t* dst, long n) {
    int blocks = (int)((n / 8 + 255) / 256); if (blocks > 8192) blocks = 8192;
    hipLaunchKernelGGL(cvt_f32_bf16, dim3(blocks), dim3(256), 0, stream, src, dst, n);
  };

  cvt(x, h16, (long)NM * ND);
  if (allw) {
    cvt(qkvw, WQ, (long)NL * 1536 * ND);
    cvt(kvw,  WK, (long)NL * 1024 * ND);
    cvt(w1p,  W1, (long)NL * NDFF * ND);
    cvt(w2p,  W2, (long)NL * ND * NDFF);
  }

  for (int l = 0; l < NL; ++l) {
    const bf16_t *wq_l, *wk_l, *w1_l, *w2_l;
    if (allw) {
      wq_l = WQ + (size_t)l * 1536 * ND;
      wk_l = WK + (size_t)l * 1024 * ND;
      w1_l = W1 + (size_t)l * NDFF * ND;
      w2_l = W2 + (size_t)l * ND * NDFF;
    } else {
      cvt(qkvw + (size_t)l * 1536 * ND, WQ, (long)1536 * ND);
      cvt(kvw  + (size_t)l * 1024 * ND, WK, (long)1024 * ND);
      cvt(w1p  + (size_t)l * NDFF * ND, W1, (long)NDFF * ND);
      cvt(w2p  + (size_t)l * ND * NDFF, W2, (long)ND * NDFF);
      wq_l = WQ; wk_l = WK; w1_l = W1; w2_l = W2;
    }

    for (int c = 0; c < nchunks; ++c) {
      const size_t r0 = (size_t)c * R;
      const bf16_t* h16c  = h16 + r0 * ND;
      const float*  resc  = (l == 0 ? x : (const float*)out) + r0 * ND;
      float*        outc  = out + r0 * ND;
      const float*  maskc = maskp + r0 * NS;
      bf16_t* vtS = big + (size_t)R * 1024;   // V^T overlay (self)
      bf16_t* vtC = big + (size_t)R * 512;    // V^T overlay (cross)

      // 1a) qk = h @ Wqk^T + b        (R x 1024, bf16)
      hipLaunchKernelGGL(HIP_KERNEL_NAME(gemm_bt<true, false, false>), dim3(R / 128, 8), dim3(256), 0, stream,
                         h16c, wq_l, qkvb + l * 1536, (void*)big, 1024, 512);
      // 1b) vtS = Wv @ h^T + bv(row)  (512 x R, bf16)
      hipLaunchKernelGGL(HIP_KERNEL_NAME(gemm_bt<true, false, true>), dim3(4, R / 128), dim3(256), 0, stream,
                         wq_l + (size_t)1024 * 512, h16c, qkvb + l * 1536 + 1024, (void*)vtS, R, 512);
      // 2) self-attention -> t32
      hipLaunchKernelGGL(HIP_KERNEL_NAME(attn2<0>), dim3(CB * 64), dim3(256), 0, stream,
                         big, big + 512, vtS, (const float*)nullptr, t32, 1024, 1024, R);
      // 3) x1 = LN1(h + attn) -> x132 + xy16
      hipLaunchKernelGGL(add_ln_kernel, dim3(R / 4), dim3(256), 0, stream,
                         resc, t32, ln1g + l * ND, ln1b + l * ND, x132, xy16);
      // 4a) k2 = h @ Wk2^T + b        (R x 512, bf16)
      hipLaunchKernelGGL(HIP_KERNEL_NAME(gemm_bt<true, false, false>), dim3(R / 128, 4), dim3(256), 0, stream,
                         h16c, wk_l, kvb + l * 1024, (void*)big, 512, 512);
      // 4b) vtC = Wv2 @ h^T + bv(row) (512 x R, bf16)
      hipLaunchKernelGGL(HIP_KERNEL_NAME(gemm_bt<true, false, true>), dim3(4, R / 128), dim3(256), 0, stream,
                         wk_l + (size_t)512 * 512, h16c, kvb + l * 1024 + 512, (void*)vtC, R, 512);
      // 5) cross-attention (10*tanh + mask) -> t32
      hipLaunchKernelGGL(HIP_KERNEL_NAME(attn2<1>), dim3(CB * 64), dim3(256), 0, stream,
                         xy16, big, vtC, maskc, t32, 512, 512, R);
      // 6) y = LN2(x1 + attn) -> x132 (in-place) + xy16
      hipLaunchKernelGGL(add_ln_kernel, dim3(R / 4), dim3(256), 0, stream,
                         x132, t32, ln2g + l * ND, ln2b + l * ND, x132, xy16);
      // 7) ff1 = relu(y @ w1^T + b1)  (R x 2048, bf16)
      hipLaunchKernelGGL(HIP_KERNEL_NAME(gemm_bt<true, true, false>), dim3(R / 128, 16), dim3(256), 0, stream,
                         xy16, w1_l, b1p + l * NDFF, (void*)big, 2048, 512);
      // 8) ff2 = ff1 @ w2^T + b2      (R x 512, f32)
      hipLaunchKernelGGL(HIP_KERNEL_NAME(gemm_bt<false, false, false>), dim3(R / 128, 4), dim3(256), 0, stream,
                         big, w2_l, b2p + l * ND, (void*)t32, 512, 2048);
      // 9) h' = LN3(y + ff2) -> residual (d_out) + h16
      hipLaunchKernelGGL(add_ln_kernel, dim3(R / 4), dim3(256), 0, stream,
                         x132, t32, ln3g + l * ND, ln3b + l * ND, outc, h16 + r0 * ND);
    }
  }
}

// Round 4
// 4625.234 us; speedup vs baseline: 1.4777x; 1.0761x over previous
//
#include <hip/hip_runtime.h>

// ---------------------------------------------------------------------------
// TSP transformer stack: 6 layers of {selfattn -> LN, crossattn(tanh-clip,mask)
// -> LN, FFN -> LN}. bf16 MFMA compute, fp32 residual stream / accumulation.
// R4: attn double-buffered K/V + mask prefetch, XCD-local (b,h) grouping,
// bf16 attn output, setprio on MFMA clusters, vt-GEMM grid swap.
// ---------------------------------------------------------------------------

typedef __bf16 bf16_t;
typedef __bf16 bf16x8 __attribute__((ext_vector_type(8)));
typedef __bf16 bf16x4 __attribute__((ext_vector_type(4)));
typedef float  f32x4  __attribute__((ext_vector_type(4)));

#define NB   64
#define NS   512
#define ND   512
#define NH   8
#define NHD  64
#define NL   6
#define NDFF 2048
#define NM   (NB * NS)   // 32768 rows

__device__ __forceinline__ void gld_lds16(const void* gsrc, void* lds) {
  __builtin_amdgcn_global_load_lds((__attribute__((address_space(1))) void*)gsrc,
                                   (__attribute__((address_space(3))) void*)lds,
                                   16, 0, 0);
}

// ------------------------------ f32 -> bf16 --------------------------------
__global__ __launch_bounds__(256) void cvt_f32_bf16(const float* __restrict__ in,
                                                    bf16_t* __restrict__ out,
                                                    long n) {
  long i = ((long)blockIdx.x * 256 + threadIdx.x) * 8;
  const long stride = (long)gridDim.x * 256 * 8;
  for (; i < n; i += stride) {
    f32x4 a = *(const f32x4*)(in + i);
    f32x4 b = *(const f32x4*)(in + i + 4);
    bf16x8 o;
#pragma unroll
    for (int j = 0; j < 4; ++j) { o[j] = (bf16_t)a[j]; o[j + 4] = (bf16_t)b[j]; }
    *(bf16x8*)(out + i) = o;
  }
}

// --------------------- GEMM: C[M][N] = A[M][K] @ W[N][K]^T + bias ----------
// m97 structure: 128x128 tile, BK=64, 4 waves (2x2), 16x16x32 bf16 MFMA.
// BIAS_ROW: bias indexed by output ROW. SWAPG: m-tile from blockIdx.y
// (so blocks sharing the W panel are XCD-local when gridDim.x % 8 == 0).
template<bool OUT_BF16, bool RELU, bool BIAS_ROW, bool SWAPG>
__global__ __launch_bounds__(256) void gemm_bt(const bf16_t* __restrict__ A,
                                               const bf16_t* __restrict__ W,
                                               const float* __restrict__ bias,
                                               void* __restrict__ Cout,
                                               int Nn, int Kk) {
  __shared__ __attribute__((aligned(16))) bf16_t As[128 * 64];
  __shared__ __attribute__((aligned(16))) bf16_t Bs[128 * 64];
  const int tid = threadIdx.x;
  const int l   = tid & 63;
  const int w   = tid >> 6;
  const int wr  = (w >> 1) * 64;
  const int wc  = (w & 1) * 64;
  const int m0  = (SWAPG ? blockIdx.y : blockIdx.x) * 128;
  const int n0  = (SWAPG ? blockIdx.x : blockIdx.y) * 128;
  const int l15 = l & 15, lg = l >> 4;

  const f32x4 zero = {0.f, 0.f, 0.f, 0.f};
  f32x4 acc[4][4];
#pragma unroll
  for (int i = 0; i < 4; ++i)
#pragma unroll
    for (int j = 0; j < 4; ++j) acc[i][j] = zero;

  const int srow = w * 32 + (l >> 3);   // staging row within tile
  const int scol = (l & 7) * 8;         // staging col (8 bf16 = 16B)

  for (int k0 = 0; k0 < Kk; k0 += 64) {
#pragma unroll
    for (int i = 0; i < 4; ++i) {
      gld_lds16(A + (size_t)(m0 + srow + i * 8) * Kk + k0 + scol, &As[(w * 4 + i) * 512]);
      gld_lds16(W + (size_t)(n0 + srow + i * 8) * Kk + k0 + scol, &Bs[(w * 4 + i) * 512]);
    }
    __syncthreads();
#pragma unroll
    for (int kk = 0; kk < 2; ++kk) {
      bf16x8 af[4], bw[4];
#pragma unroll
      for (int i = 0; i < 4; ++i) {
        af[i] = *(const bf16x8*)&As[(wr + i * 16 + l15) * 64 + kk * 32 + lg * 8];
        bw[i] = *(const bf16x8*)&Bs[(wc + i * 16 + l15) * 64 + kk * 32 + lg * 8];
      }
#pragma unroll
      for (int mi = 0; mi < 4; ++mi)
#pragma unroll
        for (int ni = 0; ni < 4; ++ni)
          acc[mi][ni] = __builtin_amdgcn_mfma_f32_16x16x32_bf16(af[mi], bw[ni], acc[mi][ni], 0, 0, 0);
    }
    __syncthreads();
  }

#pragma unroll
  for (int mi = 0; mi < 4; ++mi)
#pragma unroll
    for (int ni = 0; ni < 4; ++ni) {
      const int col = n0 + wc + ni * 16 + l15;
      const float bcol = BIAS_ROW ? 0.f : bias[col];
#pragma unroll
      for (int r = 0; r < 4; ++r) {
        const int rowi = m0 + wr + mi * 16 + lg * 4 + r;
        float v = acc[mi][ni][r] + (BIAS_ROW ? bias[rowi] : bcol);
        if (RELU) v = fmaxf(v, 0.f);
        if (OUT_BF16) ((bf16_t*)Cout)[(size_t)rowi * Nn + col] = (bf16_t)v;
        else          ((float*)Cout)[(size_t)rowi * Nn + col]  = v;
      }
    }
}

// ------------------------------- attention ---------------------------------
// One WG = (local batch, head, 64-row Q tile), 4 waves x 16 q-rows.
// Swapped QK^T (mfma(K,Q)); V consumed pre-transposed (Vt[d][s]).
// Double-buffered K/V staging + mask register prefetch: stage kt+1 during
// kt's compute; one barrier per iteration. LDS = 80KB -> 2 WG/CU.
// blockIdx decode keeps the 8 qt-WGs of one (b,h) on one XCD.
template<int CROSS>
__global__ __launch_bounds__(256, 2) void attn3(const bf16_t* __restrict__ Q,
                                                const bf16_t* __restrict__ K,
                                                const bf16_t* __restrict__ Vt,
                                                const float* __restrict__ maskp,
                                                bf16_t* __restrict__ O,
                                                int qstride, int kstride, int vstride) {
  __shared__ __attribute__((aligned(16))) bf16_t k_s[2][128 * 64];  // [k][d]
  __shared__ __attribute__((aligned(16))) bf16_t v_s[2][64 * 128];  // [d][k]
  __shared__ __attribute__((aligned(16))) bf16_t p_s[64 * 128];     // [q][k]

  const int tid = threadIdx.x;
  const int l   = tid & 63;
  const int w   = tid >> 6;
  const int bid = blockIdx.x;
  const int h   = bid & 7;             // XCD-local: 8 qt share (b,h) K/V panel
  const int qt  = (bid >> 3) & 7;
  const int b   = bid >> 6;            // chunk-local batch
  const int h64 = h * NHD;
  const int l15 = l & 15, lg = l >> 4;

  const int qglob = qt * 64 + w * 16 + l15;          // this lane's softmax q-row

  auto stageK = [&](int kt, int buf) {
#pragma unroll
    for (int i = 0; i < 4; ++i) {
      const int r  = (w * 4 + i) * 8 + (l >> 3);
      const int c8 = (l & 7) ^ (r & 7);
      gld_lds16(K + (size_t)(b * NS + kt * 128 + r) * kstride + h64 + c8 * 8,
                &k_s[buf][(w * 4 + i) * 512]);
    }
  };
  auto stageV = [&](int kt, int buf) {
#pragma unroll
    for (int i = 0; i < 4; ++i) {
      const int d = w * 16 + i * 4 + (l >> 4);
      const int g = (l & 15) ^ (d & 15);
      gld_lds16(Vt + (size_t)(h64 + d) * vstride + b * NS + kt * 128 + g * 8,
                &v_s[buf][(w * 16 + i * 4) * 128]);
    }
  };

  stageK(0, 0); stageV(0, 0);

  // Q fragments (B-operand): B[n=q(l15)][kd = c*32 + lg*8 + j]
  bf16x8 qf[2];
#pragma unroll
  for (int c = 0; c < 2; ++c)
    qf[c] = *(const bf16x8*)(Q + (size_t)(b * NS + qglob) * qstride + h64 + c * 32 + lg * 8);

  f32x4 mk[2][8];
  if (CROSS) {
#pragma unroll
    for (int nt = 0; nt < 8; ++nt)
      mk[0][nt] = *(const f32x4*)(maskp + (size_t)(b * NS + qglob) * NS + nt * 16 + lg * 4);
  }

  float m_run = -3e38f, l_run = 0.f;
  const f32x4 zz = {0.f, 0.f, 0.f, 0.f};
  f32x4 oacc[4] = {zz, zz, zz, zz};

#pragma unroll
  for (int kt = 0; kt < 4; ++kt) {
    const int buf = kt & 1;
    __syncthreads();                       // staged K/V(kt) + mask(kt) in flight -> ready
    if (kt < 3) {                          // prefetch next tile during compute
      stageK(kt + 1, buf ^ 1);
      stageV(kt + 1, buf ^ 1);
      if (CROSS) {
#pragma unroll
        for (int nt = 0; nt < 8; ++nt)
          mk[(kt + 1) & 1][nt] = *(const f32x4*)(maskp + (size_t)(b * NS + qglob) * NS
                                                 + (kt + 1) * 128 + nt * 16 + lg * 4);
      }
    }

    // ---- QK^T (swapped): s[nt] holds S[k = nt*16+lg*4+r][q = l15-local] ----
    f32x4 s[8];
    __builtin_amdgcn_s_setprio(1);
#pragma unroll
    for (int nt = 0; nt < 8; ++nt) {
      const int row = nt * 16 + l15;   // k-row
      bf16x8 ka0 = *(const bf16x8*)((const char*)k_s[buf] + row * 128 + ((lg ^ (row & 7)) * 16));
      bf16x8 ka1 = *(const bf16x8*)((const char*)k_s[buf] + row * 128 + (((4 + lg) ^ (row & 7)) * 16));
      f32x4 z = zz;
      z = __builtin_amdgcn_mfma_f32_16x16x32_bf16(ka0, qf[0], z, 0, 0, 0);
      z = __builtin_amdgcn_mfma_f32_16x16x32_bf16(ka1, qf[1], z, 0, 0, 0);
      s[nt] = z;
    }
    __builtin_amdgcn_s_setprio(0);

    // ---- scale (+clip/mask), online softmax update ----
    float tmax = -3e38f;
#pragma unroll
    for (int nt = 0; nt < 8; ++nt) {
      f32x4 v = s[nt] * 0.125f;        // 1/sqrt(64)
      if (CROSS) {
#pragma unroll
        for (int r = 0; r < 4; ++r) {
          const float e2 = __expf(2.f * v[r]);
          v[r] = 10.f - 20.f * __builtin_amdgcn_rcpf(e2 + 1.f) + mk[buf][nt][r];
        }
      }
      s[nt] = v;
#pragma unroll
      for (int r = 0; r < 4; ++r) tmax = fmaxf(tmax, v[r]);
    }
    tmax = fmaxf(tmax, __shfl_xor(tmax, 16, 64));
    tmax = fmaxf(tmax, __shfl_xor(tmax, 32, 64));
    const float m_new = fmaxf(m_run, tmax);
    const float f = __expf(m_run - m_new);
    float fq[4];
#pragma unroll
    for (int r = 0; r < 4; ++r) fq[r] = __shfl(f, lg * 4 + r, 64);
#pragma unroll
    for (int dt = 0; dt < 4; ++dt)
#pragma unroll
      for (int r = 0; r < 4; ++r) oacc[dt][r] *= fq[r];

    float ts = 0.f;
#pragma unroll
    for (int nt = 0; nt < 8; ++nt) {
      f32x4 v = s[nt];
#pragma unroll
      for (int r = 0; r < 4; ++r) { const float e = __expf(v[r] - m_new); ts += e; v[r] = e; }
      s[nt] = v;
    }
    l_run = l_run * f + ts;
    m_run = m_new;

    // ---- pack P (bf16) -> p_s rows w*16+l15, b64 writes, swz granule ^row&15 ----
    const int prow = w * 16 + l15;
#pragma unroll
    for (int nt = 0; nt < 8; ++nt) {
      bf16x4 pk;
#pragma unroll
      for (int r = 0; r < 4; ++r) pk[r] = (bf16_t)s[nt][r];
      const int gran = (nt * 2 + (lg >> 1)) ^ (prow & 15);
      *(bf16x4*)((char*)p_s + prow * 256 + gran * 16 + (lg & 1) * 8) = pk;
    }

    // ---- PV: oacc[dt] += P[q][k] * Vt[d][k] ----
    __builtin_amdgcn_s_setprio(1);
#pragma unroll
    for (int ks = 0; ks < 4; ++ks) {
      const int ag = (ks * 4 + lg) ^ (prow & 15);
      bf16x8 pa = *(const bf16x8*)((const char*)p_s + prow * 256 + ag * 16);
#pragma unroll
      for (int dt = 0; dt < 4; ++dt) {
        const int vrow = dt * 16 + l15;
        const int vg   = (ks * 4 + lg) ^ (vrow & 15);
        bf16x8 vb = *(const bf16x8*)((const char*)v_s[buf] + vrow * 256 + vg * 16);
        oacc[dt] = __builtin_amdgcn_mfma_f32_16x16x32_bf16(pa, vb, oacc[dt], 0, 0, 0);
      }
    }
    __builtin_amdgcn_s_setprio(0);
  }

  // ---- finalize: 1/rowsum, redistribute to O-layout rows, store bf16 ----
  l_run += __shfl_xor(l_run, 16, 64);
  l_run += __shfl_xor(l_run, 32, 64);
  const float inv = 1.f / l_run;
  float invq[4];
#pragma unroll
  for (int r = 0; r < 4; ++r) invq[r] = __shfl(inv, lg * 4 + r, 64);
#pragma unroll
  for (int dt = 0; dt < 4; ++dt)
#pragma unroll
    for (int r = 0; r < 4; ++r) {
      const size_t row = (size_t)(b * NS + qt * 64 + w * 16 + lg * 4 + r);
      O[row * ND + h64 + dt * 16 + l15] = (bf16_t)(oacc[dt][r] * invq[r]);
    }
}

// --------------------------- fused add + LayerNorm -------------------------
// XB16: Xb is bf16 (attn output). Xa and o32 may alias (in-place).
template<bool XB16>
__global__ __launch_bounds__(256) void add_ln_kernel(const float* Xa,
                                                     const void* __restrict__ Xbv,
                                                     const float* __restrict__ gw,
                                                     const float* __restrict__ bw,
                                                     float* o32,
                                                     bf16_t* __restrict__ o16) {
  const int l = threadIdx.x & 63;
  const size_t row = (size_t)blockIdx.x * 4 + (threadIdx.x >> 6);
  const f32x4* pa = (const f32x4*)(Xa + row * ND);
  f32x4 vb0, vb1;
  if (XB16) {
    const bf16_t* Xb = (const bf16_t*)Xbv;
    bf16x4 t0 = *(const bf16x4*)(Xb + row * ND + l * 4);
    bf16x4 t1 = *(const bf16x4*)(Xb + row * ND + 256 + l * 4);
#pragma unroll
    for (int i = 0; i < 4; ++i) { vb0[i] = (float)t0[i]; vb1[i] = (float)t1[i]; }
  } else {
    const f32x4* pb = (const f32x4*)((const float*)Xbv + row * ND);
    vb0 = pb[l]; vb1 = pb[l + 64];
  }
  f32x4 v0 = pa[l] + vb0;
  f32x4 v1 = pa[l + 64] + vb1;
  float s = v0[0] + v0[1] + v0[2] + v0[3] + v1[0] + v1[1] + v1[2] + v1[3];
#pragma unroll
  for (int off = 1; off < 64; off <<= 1) s += __shfl_xor(s, off, 64);
  const float mean = s * (1.f / ND);
  f32x4 d0 = v0 - mean, d1 = v1 - mean;
  float q = d0[0]*d0[0] + d0[1]*d0[1] + d0[2]*d0[2] + d0[3]*d0[3]
          + d1[0]*d1[0] + d1[1]*d1[1] + d1[2]*d1[2] + d1[3]*d1[3];
#pragma unroll
  for (int off = 1; off < 64; off <<= 1) q += __shfl_xor(q, off, 64);
  const float rstd = rsqrtf(q * (1.f / ND) + 1e-5f);
  const f32x4 g0 = ((const f32x4*)gw)[l], g1 = ((const f32x4*)gw)[l + 64];
  const f32x4 b0 = ((const f32x4*)bw)[l], b1 = ((const f32x4*)bw)[l + 64];
  f32x4 r0 = d0 * rstd * g0 + b0;
  f32x4 r1 = d1 * rstd * g1 + b1;
  ((f32x4*)(o32 + row * ND))[l]      = r0;
  ((f32x4*)(o32 + row * ND))[l + 64] = r1;
  bf16x4 c0, c1;
#pragma unroll
  for (int i = 0; i < 4; ++i) { c0[i] = (bf16_t)r0[i]; c1[i] = (bf16_t)r1[i]; }
  *(bf16x4*)(o16 + row * ND + l * 4)       = c0;
  *(bf16x4*)(o16 + row * ND + 256 + l * 4) = c1;
}

// ---------------------------------------------------------------------------
extern "C" void kernel_launch(void* const* d_in, const int* in_sizes, int n_in,
                              void* d_out, int out_size, void* d_ws, size_t ws_size,
                              hipStream_t stream) {
  (void)in_sizes; (void)n_in; (void)out_size;
  const float* x     = (const float*)d_in[0];
  const float* maskp = (const float*)d_in[1];
  const float* qkvw  = (const float*)d_in[2];
  const float* qkvb  = (const float*)d_in[3];
  const float* ln1g  = (const float*)d_in[4];
  const float* ln1b  = (const float*)d_in[5];
  const float* kvw   = (const float*)d_in[6];
  const float* kvb   = (const float*)d_in[7];
  const float* ln2g  = (const float*)d_in[8];
  const float* ln2b  = (const float*)d_in[9];
  const float* w1p   = (const float*)d_in[10];
  const float* b1p   = (const float*)d_in[11];
  const float* w2p   = (const float*)d_in[12];
  const float* b2p   = (const float*)d_in[13];
  const float* ln3g  = (const float*)d_in[14];
  const float* ln3b  = (const float*)d_in[15];
  float* out = (float*)d_out;

  // ---- workspace tiers: per-row = big 4096B + t32 2048 + x132 2048 + xy16 1024
  const size_t WALL = 40894464, WLYR = 6815744, H16B = 33554432;
  struct Tier { int R; bool allw; };
  const Tier tiers[6] = {{32768, true}, {16384, true}, {8192, true},
                         {4096, true}, {2048, false}, {1024, false}};
  int R = 0; bool allw = false;
  for (int t = 0; t < 6; ++t) {
    size_t need = (tiers[t].allw ? WALL : WLYR) + H16B +
                  (size_t)tiers[t].R * 9216 + 16384;
    if (ws_size >= need) { R = tiers[t].R; allw = tiers[t].allw; break; }
  }
  if (R == 0) return;
  const int nchunks = NM / R;
  const int CB = R / NS;               // batches per chunk

  char* p = (char*)d_ws;
  auto alloc = [&](size_t bytes) { char* r = p; p += (bytes + 255) & ~(size_t)255; return r; };
  bf16_t* WQ = (bf16_t*)alloc((allw ? NL : 1) * (size_t)1536 * ND * 2);
  bf16_t* WK = (bf16_t*)alloc((allw ? NL : 1) * (size_t)1024 * ND * 2);
  bf16_t* W1 = (bf16_t*)alloc((allw ? NL : 1) * (size_t)NDFF * ND * 2);
  bf16_t* W2 = (bf16_t*)alloc((allw ? NL : 1) * (size_t)ND * NDFF * 2);
  bf16_t* h16  = (bf16_t*)alloc((size_t)NM * ND * 2);
  bf16_t* big  = (bf16_t*)alloc((size_t)R * NDFF * 2);   // qk/kv + vt overlay + ff1
  float*  t32  = (float*)alloc((size_t)R * ND * 4);      // ff2 out (f32) / attn out (bf16 overlay)
  float*  x132 = (float*)alloc((size_t)R * ND * 4);      // x1 f32, then y f32 in-place
  bf16_t* xy16 = (bf16_t*)alloc((size_t)R * ND * 2);     // x1 bf16, then y bf16
  bf16_t* t16  = (bf16_t*)t32;                           // attn out overlay

  auto cvt = [&](const float* src, bf16_t* dst, long n) {
    int blocks = (int)((n / 8 + 255) / 256); if (blocks > 8192) blocks = 8192;
    hipLaunchKernelGGL(cvt_f32_bf16, dim3(blocks), dim3(256), 0, stream, src, dst, n);
  };

  cvt(x, h16, (long)NM * ND);
  if (allw) {
    cvt(qkvw, WQ, (long)NL * 1536 * ND);
    cvt(kvw,  WK, (long)NL * 1024 * ND);
    cvt(w1p,  W1, (long)NL * NDFF * ND);
    cvt(w2p,  W2, (long)NL * ND * NDFF);
  }

  for (int l = 0; l < NL; ++l) {
    const bf16_t *wq_l, *wk_l, *w1_l, *w2_l;
    if (allw) {
      wq_l = WQ + (size_t)l * 1536 * ND;
      wk_l = WK + (size_t)l * 1024 * ND;
      w1_l = W1 + (size_t)l * NDFF * ND;
      w2_l = W2 + (size_t)l * ND * NDFF;
    } else {
      cvt(qkvw + (size_t)l * 1536 * ND, WQ, (long)1536 * ND);
      cvt(kvw  + (size_t)l * 1024 * ND, WK, (long)1024 * ND);
      cvt(w1p  + (size_t)l * NDFF * ND, W1, (long)NDFF * ND);
      cvt(w2p  + (size_t)l * ND * NDFF, W2, (long)ND * NDFF);
      wq_l = WQ; wk_l = WK; w1_l = W1; w2_l = W2;
    }

    for (int c = 0; c < nchunks; ++c) {
      const size_t r0 = (size_t)c * R;
      const bf16_t* h16c  = h16 + r0 * ND;
      const float*  resc  = (l == 0 ? x : (const float*)out) + r0 * ND;
      float*        outc  = out + r0 * ND;
      const float*  maskc = maskp + r0 * NS;
      bf16_t* vtS = big + (size_t)R * 1024;   // V^T overlay (self)
      bf16_t* vtC = big + (size_t)R * 512;    // V^T overlay (cross)

      // 1a) qk = h @ Wqk^T + b        (R x 1024, bf16)
      hipLaunchKernelGGL(HIP_KERNEL_NAME(gemm_bt<true, false, false, false>), dim3(R / 128, 8), dim3(256), 0, stream,
                         h16c, wq_l, qkvb + l * 1536, (void*)big, 1024, 512);
      // 1b) vtS = Wv @ h^T + bv(row)  (512 x R, bf16), h-panel XCD-local
      hipLaunchKernelGGL(HIP_KERNEL_NAME(gemm_bt<true, false, true, true>), dim3(R / 128, 4), dim3(256), 0, stream,
                         wq_l + (size_t)1024 * 512, h16c, qkvb + l * 1536 + 1024, (void*)vtS, R, 512);
      // 2) self-attention -> t16
      hipLaunchKernelGGL(HIP_KERNEL_NAME(attn3<0>), dim3(CB * 64), dim3(256), 0, stream,
                         big, big + 512, vtS, (const float*)nullptr, t16, 1024, 1024, R);
      // 3) x1 = LN1(h + attn) -> x132 + xy16
      hipLaunchKernelGGL(HIP_KERNEL_NAME(add_ln_kernel<true>), dim3(R / 4), dim3(256), 0, stream,
                         resc, (const void*)t16, ln1g + l * ND, ln1b + l * ND, x132, xy16);
      // 4a) k2 = h @ Wk2^T + b        (R x 512, bf16)
      hipLaunchKernelGGL(HIP_KERNEL_NAME(gemm_bt<true, false, false, false>), dim3(R / 128, 4), dim3(256), 0, stream,
                         h16c, wk_l, kvb + l * 1024, (void*)big, 512, 512);
      // 4b) vtC = Wv2 @ h^T + bv(row) (512 x R, bf16)
      hipLaunchKernelGGL(HIP_KERNEL_NAME(gemm_bt<true, false, true, true>), dim3(R / 128, 4), dim3(256), 0, stream,
                         wk_l + (size_t)512 * 512, h16c, kvb + l * 1024 + 512, (void*)vtC, R, 512);
      // 5) cross-attention (10*tanh + mask) -> t16
      hipLaunchKernelGGL(HIP_KERNEL_NAME(attn3<1>), dim3(CB * 64), dim3(256), 0, stream,
                         xy16, big, vtC, maskc, t16, 512, 512, R);
      // 6) y = LN2(x1 + attn) -> x132 (in-place) + xy16
      hipLaunchKernelGGL(HIP_KERNEL_NAME(add_ln_kernel<true>), dim3(R / 4), dim3(256), 0, stream,
                         x132, (const void*)t16, ln2g + l * ND, ln2b + l * ND, x132, xy16);
      // 7) ff1 = relu(y @ w1^T + b1)  (R x 2048, bf16)
      hipLaunchKernelGGL(HIP_KERNEL_NAME(gemm_bt<true, true, false, false>), dim3(R / 128, 16), dim3(256), 0, stream,
                         xy16, w1_l, b1p + l * NDFF, (void*)big, 2048, 512);
      // 8) ff2 = ff1 @ w2^T + b2      (R x 512, f32)
      hipLaunchKernelGGL(HIP_KERNEL_NAME(gemm_bt<false, false, false, false>), dim3(R / 128, 4), dim3(256), 0, stream,
                         big, w2_l, b2p + l * ND, (void*)t32, 512, 2048);
      // 9) h' = LN3(y + ff2) -> residual (d_out) + h16
      hipLaunchKernelGGL(HIP_KERNEL_NAME(add_ln_kernel<false>), dim3(R / 4), dim3(256), 0, stream,
                         x132, (const void*)t32, ln3g + l * ND, ln3b + l * ND, outc, h16 + r0 * ND);
    }
  }
}

// Round 5
// 4597.203 us; speedup vs baseline: 1.4867x; 1.0061x over previous
//
#include <hip/hip_runtime.h>

// ---------------------------------------------------------------------------
// TSP transformer stack: 6 layers of {selfattn -> LN, crossattn(tanh-clip,mask)
// -> LN, FFN -> LN}. bf16 MFMA compute, fp32 residual stream / accumulation.
// R5: 256x256 deep-pipelined GEMM (8 waves, counted vmcnt, T2 swizzle, setprio),
// attn3 / add_ln unchanged from R4.
// ---------------------------------------------------------------------------

typedef __bf16 bf16_t;
typedef __bf16 bf16x8 __attribute__((ext_vector_type(8)));
typedef __bf16 bf16x4 __attribute__((ext_vector_type(4)));
typedef float  f32x4  __attribute__((ext_vector_type(4)));

#define NB   64
#define NS   512
#define ND   512
#define NH   8
#define NHD  64
#define NL   6
#define NDFF 2048
#define NM   (NB * NS)   // 32768 rows

__device__ __forceinline__ void gld_lds16(const void* gsrc, void* lds) {
  __builtin_amdgcn_global_load_lds((__attribute__((address_space(1))) void*)gsrc,
                                   (__attribute__((address_space(3))) void*)lds,
                                   16, 0, 0);
}

template<int N> __device__ __forceinline__ void vm_wait() {
  if constexpr (N == 0)      asm volatile("s_waitcnt vmcnt(0)" ::: "memory");
  else if constexpr (N == 2) asm volatile("s_waitcnt vmcnt(2)" ::: "memory");
  else if constexpr (N == 6) asm volatile("s_waitcnt vmcnt(6)" ::: "memory");
}

// ------------------------------ f32 -> bf16 --------------------------------
__global__ __launch_bounds__(256) void cvt_f32_bf16(const float* __restrict__ in,
                                                    bf16_t* __restrict__ out,
                                                    long n) {
  long i = ((long)blockIdx.x * 256 + threadIdx.x) * 8;
  const long stride = (long)gridDim.x * 256 * 8;
  for (; i < n; i += stride) {
    f32x4 a = *(const f32x4*)(in + i);
    f32x4 b = *(const f32x4*)(in + i + 4);
    bf16x8 o;
#pragma unroll
    for (int j = 0; j < 4; ++j) { o[j] = (bf16_t)a[j]; o[j + 4] = (bf16_t)b[j]; }
    *(bf16x8*)(out + i) = o;
  }
}

// ---------------- GEMM 256x256: C[M][N] = A[M][K] @ W[N][K]^T + bias -------
// 512 thr / 8 waves (2M x 4N), BK=64, dbuf LDS 128KB, counted vmcnt pipeline,
// 16B-granule XOR swizzle (pre-swizzled gld_lds source + swizzled ds_read).
// Piece order per K-tile prefetch: ph0:{A0,A2} ph1:{B0..B3} ph3:{A1,A3}.
// Waits: ph0 vmcnt(2) (only {A1,A3} may be in flight); ph2 vmcnt(6) (only
// next tile's 6 older pieces in flight), vmcnt(0) at the last tile.
template<bool OUT_BF16, bool RELU, bool BIAS_ROW>
__global__ __launch_bounds__(512, 2) void gemm256(const bf16_t* __restrict__ Ap,
                                                  const bf16_t* __restrict__ Wp,
                                                  const float* __restrict__ bias,
                                                  void* __restrict__ Cout,
                                                  int Nn, int Kk) {
  __shared__ __attribute__((aligned(16))) bf16_t As[2][256 * 64];
  __shared__ __attribute__((aligned(16))) bf16_t Bs[2][256 * 64];
  const int tid = threadIdx.x;
  const int l   = tid & 63;
  const int w   = tid >> 6;
  const int wr  = w >> 2;          // 0..1 (M half)
  const int wc  = w & 3;           // 0..3 (N quarter)
  const int l15 = l & 15, lg = l >> 4;

  // XCD-chunked decode (nwg % 8 == 0 for all our shapes), n fastest
  const int nn   = Nn >> 8;
  const int nwg  = gridDim.x;
  const int flat = blockIdx.x;
  const int wgid = (nwg & 7) ? flat : (flat & 7) * (nwg >> 3) + (flat >> 3);
  const int m0 = (wgid / nn) * 256;
  const int n0 = (wgid % nn) * 256;

  // stage piece p (64 rows) of A or B for K-col kc into buffer bf_
  auto stA = [&](int bf_, int p, int kc) {
    const int row = p * 64 + (tid >> 3);
    const int g   = (tid & 7) ^ (row & 7);
    gld_lds16(Ap + (size_t)(m0 + row) * Kk + kc + g * 8,
              &As[bf_][(p * 64 + w * 8) * 64]);
  };
  auto stB = [&](int bf_, int p, int kc) {
    const int row = p * 64 + (tid >> 3);
    const int g   = (tid & 7) ^ (row & 7);
    gld_lds16(Wp + (size_t)(n0 + row) * Kk + kc + g * 8,
              &Bs[bf_][(p * 64 + w * 8) * 64]);
  };
  // swizzled fragment reads
  auto ldA = [&](int bf_, int half, int mi, int ks) -> bf16x8 {
    const int row = wr * 128 + half * 64 + mi * 16 + l15;
    const int g   = (ks * 4 + lg) ^ (row & 7);
    return *(const bf16x8*)&As[bf_][row * 64 + g * 8];
  };
  auto ldB = [&](int bf_, int ni, int ks) -> bf16x8 {
    const int row = wc * 64 + ni * 16 + l15;
    const int g   = (ks * 4 + lg) ^ (row & 7);
    return *(const bf16x8*)&Bs[bf_][row * 64 + g * 8];
  };

  f32x4 acc[8][4];
#pragma unroll
  for (int i = 0; i < 8; ++i)
#pragma unroll
    for (int j = 0; j < 4; ++j) acc[i][j] = (f32x4){0.f, 0.f, 0.f, 0.f};

  const int KT = Kk >> 6;
  // prologue: all 8 pieces of kt0 in wait-order
  stA(0, 0, 0); stA(0, 2, 0);
  stB(0, 0, 0); stB(0, 1, 0); stB(0, 2, 0); stB(0, 3, 0);
  stA(0, 1, 0); stA(0, 3, 0);

  int buf = 0;
  for (int kt = 0; kt < KT; ++kt) {
    const bool pf = (kt + 1 < KT);
    const int  nk = pf ? (kt + 1) * 64 : 0;
    bf16x8 af[4][2], bfr[4][2];

    // ---------------- phase 0: Q(m0-3, n0-1) ----------------
    vm_wait<2>();
    __builtin_amdgcn_s_barrier();
    if (pf) { stA(buf ^ 1, 0, nk); stA(buf ^ 1, 2, nk); }
#pragma unroll
    for (int mi = 0; mi < 4; ++mi)
#pragma unroll
      for (int ks = 0; ks < 2; ++ks) af[mi][ks] = ldA(buf, 0, mi, ks);
#pragma unroll
    for (int ni = 0; ni < 2; ++ni)
#pragma unroll
      for (int ks = 0; ks < 2; ++ks) bfr[ni][ks] = ldB(buf, ni, ks);
    __builtin_amdgcn_s_setprio(1);
#pragma unroll
    for (int mi = 0; mi < 4; ++mi)
#pragma unroll
      for (int ni = 0; ni < 2; ++ni)
#pragma unroll
        for (int ks = 0; ks < 2; ++ks)
          acc[mi][ni] = __builtin_amdgcn_mfma_f32_16x16x32_bf16(af[mi][ks], bfr[ni][ks], acc[mi][ni], 0, 0, 0);
    __builtin_amdgcn_s_setprio(0);

    // ---------------- phase 1: Q(m0-3, n2-3) ----------------
    if (pf) { stB(buf ^ 1, 0, nk); stB(buf ^ 1, 1, nk); stB(buf ^ 1, 2, nk); stB(buf ^ 1, 3, nk); }
#pragma unroll
    for (int ni = 2; ni < 4; ++ni)
#pragma unroll
      for (int ks = 0; ks < 2; ++ks) bfr[ni][ks] = ldB(buf, ni, ks);
    __builtin_amdgcn_s_setprio(1);
#pragma unroll
    for (int mi = 0; mi < 4; ++mi)
#pragma unroll
      for (int ni = 2; ni < 4; ++ni)
#pragma unroll
        for (int ks = 0; ks < 2; ++ks)
          acc[mi][ni] = __builtin_amdgcn_mfma_f32_16x16x32_bf16(af[mi][ks], bfr[ni][ks], acc[mi][ni], 0, 0, 0);
    __builtin_amdgcn_s_setprio(0);

    // ---------------- phase 2: Q(m4-7, n0-1) ----------------
    if (pf) vm_wait<6>(); else vm_wait<0>();
    __builtin_amdgcn_s_barrier();
#pragma unroll
    for (int mi = 0; mi < 4; ++mi)
#pragma unroll
      for (int ks = 0; ks < 2; ++ks) af[mi][ks] = ldA(buf, 1, mi, ks);
    __builtin_amdgcn_s_setprio(1);
#pragma unroll
    for (int mi = 0; mi < 4; ++mi)
#pragma unroll
      for (int ni = 0; ni < 2; ++ni)
#pragma unroll
        for (int ks = 0; ks < 2; ++ks)
          acc[mi + 4][ni] = __builtin_amdgcn_mfma_f32_16x16x32_bf16(af[mi][ks], bfr[ni][ks], acc[mi + 4][ni], 0, 0, 0);
    __builtin_amdgcn_s_setprio(0);

    // ---------------- phase 3: Q(m4-7, n2-3) ----------------
    if (pf) { stA(buf ^ 1, 1, nk); stA(buf ^ 1, 3, nk); }
    __builtin_amdgcn_s_setprio(1);
#pragma unroll
    for (int mi = 0; mi < 4; ++mi)
#pragma unroll
      for (int ni = 2; ni < 4; ++ni)
#pragma unroll
        for (int ks = 0; ks < 2; ++ks)
          acc[mi + 4][ni] = __builtin_amdgcn_mfma_f32_16x16x32_bf16(af[mi][ks], bfr[ni][ks], acc[mi + 4][ni], 0, 0, 0);
    __builtin_amdgcn_s_setprio(0);

    buf ^= 1;
  }

  // ---------------- epilogue ----------------
#pragma unroll
  for (int mf = 0; mf < 8; ++mf)
#pragma unroll
    for (int ni = 0; ni < 4; ++ni) {
      const int col = n0 + wc * 64 + ni * 16 + l15;
      const float bc = BIAS_ROW ? 0.f : bias[col];
#pragma unroll
      for (int r = 0; r < 4; ++r) {
        const int rowi = m0 + wr * 128 + mf * 16 + lg * 4 + r;
        float v = acc[mf][ni][r] + (BIAS_ROW ? bias[rowi] : bc);
        if (RELU) v = fmaxf(v, 0.f);
        if (OUT_BF16) ((bf16_t*)Cout)[(size_t)rowi * Nn + col] = (bf16_t)v;
        else          ((float*)Cout)[(size_t)rowi * Nn + col]  = v;
      }
    }
}

// ------------------------------- attention ---------------------------------
// One WG = (local batch, head, 64-row Q tile), 4 waves x 16 q-rows.
// Swapped QK^T (mfma(K,Q)); V consumed pre-transposed (Vt[d][s]).
// Double-buffered K/V staging + mask register prefetch. LDS 80KB -> 2 WG/CU.
template<int CROSS>
__global__ __launch_bounds__(256, 2) void attn3(const bf16_t* __restrict__ Q,
                                                const bf16_t* __restrict__ K,
                                                const bf16_t* __restrict__ Vt,
                                                const float* __restrict__ maskp,
                                                bf16_t* __restrict__ O,
                                                int qstride, int kstride, int vstride) {
  __shared__ __attribute__((aligned(16))) bf16_t k_s[2][128 * 64];  // [k][d]
  __shared__ __attribute__((aligned(16))) bf16_t v_s[2][64 * 128];  // [d][k]
  __shared__ __attribute__((aligned(16))) bf16_t p_s[64 * 128];     // [q][k]

  const int tid = threadIdx.x;
  const int l   = tid & 63;
  const int w   = tid >> 6;
  const int bid = blockIdx.x;
  const int h   = bid & 7;             // XCD-local: 8 qt share (b,h) K/V panel
  const int qt  = (bid >> 3) & 7;
  const int b   = bid >> 6;            // chunk-local batch
  const int h64 = h * NHD;
  const int l15 = l & 15, lg = l >> 4;

  const int qglob = qt * 64 + w * 16 + l15;          // this lane's softmax q-row

  auto stageK = [&](int kt, int buf) {
#pragma unroll
    for (int i = 0; i < 4; ++i) {
      const int r  = (w * 4 + i) * 8 + (l >> 3);
      const int c8 = (l & 7) ^ (r & 7);
      gld_lds16(K + (size_t)(b * NS + kt * 128 + r) * kstride + h64 + c8 * 8,
                &k_s[buf][(w * 4 + i) * 512]);
    }
  };
  auto stageV = [&](int kt, int buf) {
#pragma unroll
    for (int i = 0; i < 4; ++i) {
      const int d = w * 16 + i * 4 + (l >> 4);
      const int g = (l & 15) ^ (d & 15);
      gld_lds16(Vt + (size_t)(h64 + d) * vstride + b * NS + kt * 128 + g * 8,
                &v_s[buf][(w * 16 + i * 4) * 128]);
    }
  };

  stageK(0, 0); stageV(0, 0);

  // Q fragments (B-operand): B[n=q(l15)][kd = c*32 + lg*8 + j]
  bf16x8 qf[2];
#pragma unroll
  for (int c = 0; c < 2; ++c)
    qf[c] = *(const bf16x8*)(Q + (size_t)(b * NS + qglob) * qstride + h64 + c * 32 + lg * 8);

  f32x4 mk[2][8];
  if (CROSS) {
#pragma unroll
    for (int nt = 0; nt < 8; ++nt)
      mk[0][nt] = *(const f32x4*)(maskp + (size_t)(b * NS + qglob) * NS + nt * 16 + lg * 4);
  }

  float m_run = -3e38f, l_run = 0.f;
  const f32x4 zz = {0.f, 0.f, 0.f, 0.f};
  f32x4 oacc[4] = {zz, zz, zz, zz};

#pragma unroll
  for (int kt = 0; kt < 4; ++kt) {
    const int buf = kt & 1;
    __syncthreads();                       // staged K/V(kt) + mask(kt) ready
    if (kt < 3) {                          // prefetch next tile during compute
      stageK(kt + 1, buf ^ 1);
      stageV(kt + 1, buf ^ 1);
      if (CROSS) {
#pragma unroll
        for (int nt = 0; nt < 8; ++nt)
          mk[(kt + 1) & 1][nt] = *(const f32x4*)(maskp + (size_t)(b * NS + qglob) * NS
                                                 + (kt + 1) * 128 + nt * 16 + lg * 4);
      }
    }

    // ---- QK^T (swapped): s[nt] holds S[k = nt*16+lg*4+r][q = l15-local] ----
    f32x4 s[8];
    __builtin_amdgcn_s_setprio(1);
#pragma unroll
    for (int nt = 0; nt < 8; ++nt) {
      const int row = nt * 16 + l15;   // k-row
      bf16x8 ka0 = *(const bf16x8*)((const char*)k_s[buf] + row * 128 + ((lg ^ (row & 7)) * 16));
      bf16x8 ka1 = *(const bf16x8*)((const char*)k_s[buf] + row * 128 + (((4 + lg) ^ (row & 7)) * 16));
      f32x4 z = zz;
      z = __builtin_amdgcn_mfma_f32_16x16x32_bf16(ka0, qf[0], z, 0, 0, 0);
      z = __builtin_amdgcn_mfma_f32_16x16x32_bf16(ka1, qf[1], z, 0, 0, 0);
      s[nt] = z;
    }
    __builtin_amdgcn_s_setprio(0);

    // ---- scale (+clip/mask), online softmax update ----
    float tmax = -3e38f;
#pragma unroll
    for (int nt = 0; nt < 8; ++nt) {
      f32x4 v = s[nt] * 0.125f;        // 1/sqrt(64)
      if (CROSS) {
#pragma unroll
        for (int r = 0; r < 4; ++r) {
          const float e2 = __expf(2.f * v[r]);
          v[r] = 10.f - 20.f * __builtin_amdgcn_rcpf(e2 + 1.f) + mk[buf][nt][r];
        }
      }
      s[nt] = v;
#pragma unroll
      for (int r = 0; r < 4; ++r) tmax = fmaxf(tmax, v[r]);
    }
    tmax = fmaxf(tmax, __shfl_xor(tmax, 16, 64));
    tmax = fmaxf(tmax, __shfl_xor(tmax, 32, 64));
    const float m_new = fmaxf(m_run, tmax);
    const float f = __expf(m_run - m_new);
    float fq[4];
#pragma unroll
    for (int r = 0; r < 4; ++r) fq[r] = __shfl(f, lg * 4 + r, 64);
#pragma unroll
    for (int dt = 0; dt < 4; ++dt)
#pragma unroll
      for (int r = 0; r < 4; ++r) oacc[dt][r] *= fq[r];

    float ts = 0.f;
#pragma unroll
    for (int nt = 0; nt < 8; ++nt) {
      f32x4 v = s[nt];
#pragma unroll
      for (int r = 0; r < 4; ++r) { const float e = __expf(v[r] - m_new); ts += e; v[r] = e; }
      s[nt] = v;
    }
    l_run = l_run * f + ts;
    m_run = m_new;

    // ---- pack P (bf16) -> p_s rows w*16+l15, b64 writes, swz granule ^row&15 ----
    const int prow = w * 16 + l15;
#pragma unroll
    for (int nt = 0; nt < 8; ++nt) {
      bf16x4 pk;
#pragma unroll
      for (int r = 0; r < 4; ++r) pk[r] = (bf16_t)s[nt][r];
      const int gran = (nt * 2 + (lg >> 1)) ^ (prow & 15);
      *(bf16x4*)((char*)p_s + prow * 256 + gran * 16 + (lg & 1) * 8) = pk;
    }

    // ---- PV: oacc[dt] += P[q][k] * Vt[d][k] ----
    __builtin_amdgcn_s_setprio(1);
#pragma unroll
    for (int ks = 0; ks < 4; ++ks) {
      const int ag = (ks * 4 + lg) ^ (prow & 15);
      bf16x8 pa = *(const bf16x8*)((const char*)p_s + prow * 256 + ag * 16);
#pragma unroll
      for (int dt = 0; dt < 4; ++dt) {
        const int vrow = dt * 16 + l15;
        const int vg   = (ks * 4 + lg) ^ (vrow & 15);
        bf16x8 vb = *(const bf16x8*)((const char*)v_s[buf] + vrow * 256 + vg * 16);
        oacc[dt] = __builtin_amdgcn_mfma_f32_16x16x32_bf16(pa, vb, oacc[dt], 0, 0, 0);
      }
    }
    __builtin_amdgcn_s_setprio(0);
  }

  // ---- finalize: 1/rowsum, redistribute to O-layout rows, store bf16 ----
  l_run += __shfl_xor(l_run, 16, 64);
  l_run += __shfl_xor(l_run, 32, 64);
  const float inv = 1.f / l_run;
  float invq[4];
#pragma unroll
  for (int r = 0; r < 4; ++r) invq[r] = __shfl(inv, lg * 4 + r, 64);
#pragma unroll
  for (int dt = 0; dt < 4; ++dt)
#pragma unroll
    for (int r = 0; r < 4; ++r) {
      const size_t row = (size_t)(b * NS + qt * 64 + w * 16 + lg * 4 + r);
      O[row * ND + h64 + dt * 16 + l15] = (bf16_t)(oacc[dt][r] * invq[r]);
    }
}

// --------------------------- fused add + LayerNorm -------------------------
// XB16: Xb is bf16 (attn output). Xa and o32 may alias (in-place).
template<bool XB16>
__global__ __launch_bounds__(256) void add_ln_kernel(const float* Xa,
                                                     const void* __restrict__ Xbv,
                                                     const float* __restrict__ gw,
                                                     const float* __restrict__ bw,
                                                     float* o32,
                                                     bf16_t* __restrict__ o16) {
  const int l = threadIdx.x & 63;
  const size_t row = (size_t)blockIdx.x * 4 + (threadIdx.x >> 6);
  const f32x4* pa = (const f32x4*)(Xa + row * ND);
  f32x4 vb0, vb1;
  if (XB16) {
    const bf16_t* Xb = (const bf16_t*)Xbv;
    bf16x4 t0 = *(const bf16x4*)(Xb + row * ND + l * 4);
    bf16x4 t1 = *(const bf16x4*)(Xb + row * ND + 256 + l * 4);
#pragma unroll
    for (int i = 0; i < 4; ++i) { vb0[i] = (float)t0[i]; vb1[i] = (float)t1[i]; }
  } else {
    const f32x4* pb = (const f32x4*)((const float*)Xbv + row * ND);
    vb0 = pb[l]; vb1 = pb[l + 64];
  }
  f32x4 v0 = pa[l] + vb0;
  f32x4 v1 = pa[l + 64] + vb1;
  float s = v0[0] + v0[1] + v0[2] + v0[3] + v1[0] + v1[1] + v1[2] + v1[3];
#pragma unroll
  for (int off = 1; off < 64; off <<= 1) s += __shfl_xor(s, off, 64);
  const float mean = s * (1.f / ND);
  f32x4 d0 = v0 - mean, d1 = v1 - mean;
  float q = d0[0]*d0[0] + d0[1]*d0[1] + d0[2]*d0[2] + d0[3]*d0[3]
          + d1[0]*d1[0] + d1[1]*d1[1] + d1[2]*d1[2] + d1[3]*d1[3];
#pragma unroll
  for (int off = 1; off < 64; off <<= 1) q += __shfl_xor(q, off, 64);
  const float rstd = rsqrtf(q * (1.f / ND) + 1e-5f);
  const f32x4 g0 = ((const f32x4*)gw)[l], g1 = ((const f32x4*)gw)[l + 64];
  const f32x4 b0 = ((const f32x4*)bw)[l], b1 = ((const f32x4*)bw)[l + 64];
  f32x4 r0 = d0 * rstd * g0 + b0;
  f32x4 r1 = d1 * rstd * g1 + b1;
  ((f32x4*)(o32 + row * ND))[l]      = r0;
  ((f32x4*)(o32 + row * ND))[l + 64] = r1;
  bf16x4 c0, c1;
#pragma unroll
  for (int i = 0; i < 4; ++i) { c0[i] = (bf16_t)r0[i]; c1[i] = (bf16_t)r1[i]; }
  *(bf16x4*)(o16 + row * ND + l * 4)       = c0;
  *(bf16x4*)(o16 + row * ND + 256 + l * 4) = c1;
}

// ---------------------------------------------------------------------------
extern "C" void kernel_launch(void* const* d_in, const int* in_sizes, int n_in,
                              void* d_out, int out_size, void* d_ws, size_t ws_size,
                              hipStream_t stream) {
  (void)in_sizes; (void)n_in; (void)out_size;
  const float* x     = (const float*)d_in[0];
  const float* maskp = (const float*)d_in[1];
  const float* qkvw  = (const float*)d_in[2];
  const float* qkvb  = (const float*)d_in[3];
  const float* ln1g  = (const float*)d_in[4];
  const float* ln1b  = (const float*)d_in[5];
  const float* kvw   = (const float*)d_in[6];
  const float* kvb   = (const float*)d_in[7];
  const float* ln2g  = (const float*)d_in[8];
  const float* ln2b  = (const float*)d_in[9];
  const float* w1p   = (const float*)d_in[10];
  const float* b1p   = (const float*)d_in[11];
  const float* w2p   = (const float*)d_in[12];
  const float* b2p   = (const float*)d_in[13];
  const float* ln3g  = (const float*)d_in[14];
  const float* ln3b  = (const float*)d_in[15];
  float* out = (float*)d_out;

  // ---- workspace tiers ----
  const size_t WALL = 40894464, WLYR = 6815744, H16B = 33554432;
  struct Tier { int R; bool allw; };
  const Tier tiers[6] = {{32768, true}, {16384, true}, {8192, true},
                         {4096, true}, {2048, false}, {1024, false}};
  int R = 0; bool allw = false;
  for (int t = 0; t < 6; ++t) {
    size_t need = (tiers[t].allw ? WALL : WLYR) + H16B +
                  (size_t)tiers[t].R * 9216 + 16384;
    if (ws_size >= need) { R = tiers[t].R; allw = tiers[t].allw; break; }
  }
  if (R == 0) return;
  const int nchunks = NM / R;
  const int CB = R / NS;               // batches per chunk

  char* p = (char*)d_ws;
  auto alloc = [&](size_t bytes) { char* r = p; p += (bytes + 255) & ~(size_t)255; return r; };
  bf16_t* WQ = (bf16_t*)alloc((allw ? NL : 1) * (size_t)1536 * ND * 2);
  bf16_t* WK = (bf16_t*)alloc((allw ? NL : 1) * (size_t)1024 * ND * 2);
  bf16_t* W1 = (bf16_t*)alloc((allw ? NL : 1) * (size_t)NDFF * ND * 2);
  bf16_t* W2 = (bf16_t*)alloc((allw ? NL : 1) * (size_t)ND * NDFF * 2);
  bf16_t* h16  = (bf16_t*)alloc((size_t)NM * ND * 2);
  bf16_t* big  = (bf16_t*)alloc((size_t)R * NDFF * 2);   // qk/kv + vt overlay + ff1
  float*  t32  = (float*)alloc((size_t)R * ND * 4);      // ff2 out (f32) / attn out (bf16 overlay)
  float*  x132 = (float*)alloc((size_t)R * ND * 4);      // x1 f32, then y f32 in-place
  bf16_t* xy16 = (bf16_t*)alloc((size_t)R * ND * 2);     // x1 bf16, then y bf16
  bf16_t* t16  = (bf16_t*)t32;                           // attn out overlay

  auto cvt = [&](const float* src, bf16_t* dst, long n) {
    int blocks = (int)((n / 8 + 255) / 256); if (blocks > 8192) blocks = 8192;
    hipLaunchKernelGGL(cvt_f32_bf16, dim3(blocks), dim3(256), 0, stream, src, dst, n);
  };

  cvt(x, h16, (long)NM * ND);
  if (allw) {
    cvt(qkvw, WQ, (long)NL * 1536 * ND);
    cvt(kvw,  WK, (long)NL * 1024 * ND);
    cvt(w1p,  W1, (long)NL * NDFF * ND);
    cvt(w2p,  W2, (long)NL * ND * NDFF);
  }

  for (int l = 0; l < NL; ++l) {
    const bf16_t *wq_l, *wk_l, *w1_l, *w2_l;
    if (allw) {
      wq_l = WQ + (size_t)l * 1536 * ND;
      wk_l = WK + (size_t)l * 1024 * ND;
      w1_l = W1 + (size_t)l * NDFF * ND;
      w2_l = W2 + (size_t)l * ND * NDFF;
    } else {
      cvt(qkvw + (size_t)l * 1536 * ND, WQ, (long)1536 * ND);
      cvt(kvw  + (size_t)l * 1024 * ND, WK, (long)1024 * ND);
      cvt(w1p  + (size_t)l * NDFF * ND, W1, (long)NDFF * ND);
      cvt(w2p  + (size_t)l * ND * NDFF, W2, (long)ND * NDFF);
      wq_l = WQ; wk_l = WK; w1_l = W1; w2_l = W2;
    }

    for (int c = 0; c < nchunks; ++c) {
      const size_t r0 = (size_t)c * R;
      const bf16_t* h16c  = h16 + r0 * ND;
      const float*  resc  = (l == 0 ? x : (const float*)out) + r0 * ND;
      float*        outc  = out + r0 * ND;
      const float*  maskc = maskp + r0 * NS;
      bf16_t* vtS = big + (size_t)R * 1024;   // V^T overlay (self)
      bf16_t* vtC = big + (size_t)R * 512;    // V^T overlay (cross)

      // 1a) qk = h @ Wqk^T + b        (R x 1024, bf16)
      hipLaunchKernelGGL(HIP_KERNEL_NAME(gemm256<true, false, false>), dim3((R / 256) * 4), dim3(512), 0, stream,
                         h16c, wq_l, qkvb + l * 1536, (void*)big, 1024, 512);
      // 1b) vtS = Wv @ h^T + bv(row)  (512 x R, bf16)
      hipLaunchKernelGGL(HIP_KERNEL_NAME(gemm256<true, false, true>), dim3(2 * (R / 256)), dim3(512), 0, stream,
                         wq_l + (size_t)1024 * 512, h16c, qkvb + l * 1536 + 1024, (void*)vtS, R, 512);
      // 2) self-attention -> t16
      hipLaunchKernelGGL(HIP_KERNEL_NAME(attn3<0>), dim3(CB * 64), dim3(256), 0, stream,
                         big, big + 512, vtS, (const float*)nullptr, t16, 1024, 1024, R);
      // 3) x1 = LN1(h + attn) -> x132 + xy16
      hipLaunchKernelGGL(HIP_KERNEL_NAME(add_ln_kernel<true>), dim3(R / 4), dim3(256), 0, stream,
                         resc, (const void*)t16, ln1g + l * ND, ln1b + l * ND, x132, xy16);
      // 4a) k2 = h @ Wk2^T + b        (R x 512, bf16)
      hipLaunchKernelGGL(HIP_KERNEL_NAME(gemm256<true, false, false>), dim3((R / 256) * 2), dim3(512), 0, stream,
                         h16c, wk_l, kvb + l * 1024, (void*)big, 512, 512);
      // 4b) vtC = Wv2 @ h^T + bv(row) (512 x R, bf16)
      hipLaunchKernelGGL(HIP_KERNEL_NAME(gemm256<true, false, true>), dim3(2 * (R / 256)), dim3(512), 0, stream,
                         wk_l + (size_t)512 * 512, h16c, kvb + l * 1024 + 512, (void*)vtC, R, 512);
      // 5) cross-attention (10*tanh + mask) -> t16
      hipLaunchKernelGGL(HIP_KERNEL_NAME(attn3<1>), dim3(CB * 64), dim3(256), 0, stream,
                         xy16, big, vtC, maskc, t16, 512, 512, R);
      // 6) y = LN2(x1 + attn) -> x132 (in-place) + xy16
      hipLaunchKernelGGL(HIP_KERNEL_NAME(add_ln_kernel<true>), dim3(R / 4), dim3(256), 0, stream,
                         x132, (const void*)t16, ln2g + l * ND, ln2b + l * ND, x132, xy16);
      // 7) ff1 = relu(y @ w1^T + b1)  (R x 2048, bf16)
      hipLaunchKernelGGL(HIP_KERNEL_NAME(gemm256<true, true, false>), dim3((R / 256) * 8), dim3(512), 0, stream,
                         xy16, w1_l, b1p + l * NDFF, (void*)big, 2048, 512);
      // 8) ff2 = ff1 @ w2^T + b2      (R x 512, f32)
      hipLaunchKernelGGL(HIP_KERNEL_NAME(gemm256<false, false, false>), dim3((R / 256) * 2), dim3(512), 0, stream,
                         big, w2_l, b2p + l * ND, (void*)t32, 512, 2048);
      // 9) h' = LN3(y + ff2) -> residual (d_out) + h16
      hipLaunchKernelGGL(HIP_KERNEL_NAME(add_ln_kernel<false>), dim3(R / 4), dim3(256), 0, stream,
                         x132, (const void*)t32, ln3g + l * ND, ln3b + l * ND, outc, h16 + r0 * ND);
    }
  }
}